// Round 3
// baseline (12130.960 us; speedup 1.0000x reference)
//
#include <hip/hip_runtime.h>
#include <hip/hip_bf16.h>
#include <stdint.h>

#define LSEQ   16384
#define BATCH  32
#define HIDN   32
#define NGATE  128   // 4*HIDN
#define INDIM  64

// libm-accurate sigmoid (OCML expf, IEEE division)
__device__ __forceinline__ float fsig(float x) { return 1.f / (1.f + expf(-x)); }

// ---------------------------------------------------------------------------
// k_prep: bias2[d][j] = bih[j] + bhh[j]; zero hsum and h/c state.
// ---------------------------------------------------------------------------
__global__ __launch_bounds__(256) void k_prep(
    const float* __restrict__ bih_f, const float* __restrict__ bhh_f,
    const float* __restrict__ bih_b, const float* __restrict__ bhh_b,
    float* __restrict__ bias2, float* __restrict__ hsum, float* __restrict__ state)
{
    int gid = blockIdx.x * 256 + threadIdx.x;   // [0, 4096)
    if (gid < 256) {
        int dd = gid >> 7, jj = gid & 127;
        float bi = dd ? bih_b[jj] : bih_f[jj];
        float bh = dd ? bhh_b[jj] : bhh_f[jj];
        bias2[gid] = __fadd_rn(bi, bh);
    }
    if (gid < 2 * BATCH * HIDN) hsum[gid] = 0.f;
    if (gid < 2 * BATCH * 2 * HIDN) state[gid] = 0.f;
}

// ---------------------------------------------------------------------------
// k_gx: two-stage, mimicking numpy with exact (fp64) dots rounded to fp32 at
// the same points numpy rounds:
//   proj[m]  = round_f32( proj_b[m] + sum_k proj_W[m,k]*f[k] )      (fp64 dot)
//   gx[j]    = round_f32( (bih+bhh)[j] + sum_m Wih[j,m]*proj[m] )   (fp64 dot)
// Layout gx: [2][B][chunkT][128]; t = s (fwd) or L-1-s (bwd), s = s0+tt.
// ---------------------------------------------------------------------------
__global__ __launch_bounds__(256) void k_gx(
    const float* __restrict__ features,  // [B][64][L]
    const float* __restrict__ proj_W,    // [32][64]
    const float* __restrict__ proj_b,    // [32]
    const float* __restrict__ Wih_f,     // [128][32]
    const float* __restrict__ Wih_b,
    const float* __restrict__ bias2,     // [2][128]
    float* __restrict__ gx,
    int chunkT, int s0)
{
    int tilesPerB = chunkT >> 8;
    int b  = blockIdx.x / tilesPerB;
    int tt = (blockIdx.x % tilesPerB) * 256 + threadIdx.x;
    int s  = s0 + tt;

    #pragma unroll 1
    for (int d = 0; d < 2; ++d) {
        int t = d ? (LSEQ - 1 - s) : s;
        float f[INDIM];
        #pragma unroll
        for (int k = 0; k < INDIM; ++k)
            f[k] = features[((size_t)b * INDIM + k) * LSEQ + t];

        float proj[HIDN];
        #pragma unroll 1
        for (int m = 0; m < HIDN; ++m) {
            double a = (double)proj_b[m];
            #pragma unroll
            for (int k = 0; k < INDIM; ++k)
                a += (double)proj_W[m * INDIM + k] * (double)f[k];
            proj[m] = (float)a;
        }

        const float* Wih = d ? Wih_b : Wih_f;
        const float* bs  = bias2 + d * NGATE;
        float* out = gx + (((size_t)(d * BATCH + b) * chunkT + tt) << 7);
        #pragma unroll 1
        for (int j = 0; j < NGATE; j += 2) {
            double a0 = (double)bs[j];
            double a1 = (double)bs[j + 1];
            #pragma unroll
            for (int m = 0; m < HIDN; ++m) {
                double pm = (double)proj[m];
                a0 += (double)Wih[(j + 0) * HIDN + m] * pm;
                a1 += (double)Wih[(j + 1) * HIDN + m] * pm;
            }
            out[j]     = (float)a0;
            out[j + 1] = (float)a1;
        }
    }
}

// ---------------------------------------------------------------------------
// k_rec: sequential LSTM, one single-wave workgroup per (dir, batch).
// Lane l<32 owns gate rows i[k],f[k]; lane l>=32 owns g[k],o[k] (k=l&31).
// Whh matvec accumulated in fp64 (exact), gates rounded to fp32, activations
// via libm tanhf/expf, c/h updated with numpy's rounding pattern.
// ---------------------------------------------------------------------------
__global__ __launch_bounds__(64) void k_rec(
    const float* __restrict__ gx,      // [2][B][chunkT][128] (+pad)
    const float* __restrict__ Whh_f,   // [128][32]
    const float* __restrict__ Whh_b,
    float* __restrict__ hbuf,          // [2][B][L][32] fp32
    float* __restrict__ state,         // [2][B][2][32]  (h then c)
    float* __restrict__ hsum,          // [2][B][32]
    int chunkT, int s0)
{
    const int wg   = blockIdx.x;        // d*32 + b
    const int d    = wg >> 5;
    const int lane = threadIdx.x;
    const int k    = lane & 31;
    const int half = lane >> 5;         // 0: i/f rows, 1: g/o rows
    const int r0   = k + (half << 6);   // i or g row
    const int r1   = r0 + 32;           // f or o row

    const float* whh = d ? Whh_b : Whh_f;
    double w0[HIDN], w1[HIDN];
    #pragma unroll
    for (int m = 0; m < HIDN; ++m) {
        w0[m] = (double)whh[r0 * HIDN + m];
        w1[m] = (double)whh[r1 * HIDN + m];
    }

    __shared__ __align__(16) float h_lds[HIDN];

    float* st = state + (wg << 6);
    float h_my = 0.f, c_my = 0.f, hs_my = 0.f;
    if (lane < HIDN) {
        h_my = st[lane];
        c_my = st[HIDN + lane];
        hs_my = hsum[wg * HIDN + lane];
        h_lds[lane] = h_my;
    }
    __syncthreads();
    double hr[HIDN];
    #pragma unroll
    for (int m = 0; m < HIDN; m += 4) {
        float4 v = *reinterpret_cast<const float4*>(&h_lds[m]);
        hr[m] = (double)v.x; hr[m + 1] = (double)v.y;
        hr[m + 2] = (double)v.z; hr[m + 3] = (double)v.w;
    }

    const float* gq = gx + (((size_t)wg * chunkT) << 7);
    // prefetch pipeline depth 2
    float n0 = gq[r0],        n1 = gq[r1];          // step tt
    float m0 = gq[128 + r0],  m1 = gq[128 + r1];    // step tt+1

    const int t0 = d ? (LSEQ - 1 - s0) : s0;
    const int hinc = d ? -HIDN : HIDN;
    float* hp = hbuf + (((size_t)wg * LSEQ + t0) << 5) + k;

    for (int tt = 0; tt < chunkT; ++tt) {
        double g0 = (double)n0, g1 = (double)n1;
        n0 = m0; n1 = m1;
        gq += NGATE;
        m0 = gq[128 + r0]; m1 = gq[128 + r1];   // tt+2 (reads into pad at tail)

        #pragma unroll
        for (int m = 0; m < HIDN; ++m) {
            g0 += w0[m] * hr[m];
            g1 += w1[m] * hr[m];
        }
        float gf0 = (float)g0, gf1 = (float)g1;
        float a0 = half ? tanhf(gf0) : fsig(gf0);  // i (lo) / g (hi)
        float a1 = fsig(gf1);                       // f (lo) / o (hi)
        float xg = __shfl_xor(a0, 32);              // lo lanes: tanh(g_k)
        float xo = __shfl_xor(a1, 32);              // lo lanes: sig(o_k)
        // numpy rounding pattern: c = (f*c) + (i*g); h = o * tanh(c)
        float p1 = __fmul_rn(a1, c_my);
        float p2 = __fmul_rn(a0, xg);
        float cn = __fadd_rn(p1, p2);
        float hn = __fmul_rn(xo, tanhf(cn));
        if (lane < HIDN) {
            c_my = cn; h_my = hn;
            hs_my = __fadd_rn(hs_my, hn);
            h_lds[lane] = hn;
            *hp = hn;
        }
        hp += hinc;
        __syncthreads();
        #pragma unroll
        for (int m = 0; m < HIDN; m += 4) {
            float4 v = *reinterpret_cast<const float4*>(&h_lds[m]);
            hr[m] = (double)v.x; hr[m + 1] = (double)v.y;
            hr[m + 2] = (double)v.z; hr[m + 3] = (double)v.w;
        }
    }

    if (lane < HIDN) {
        st[lane] = h_my;
        st[HIDN + lane] = c_my;
        hsum[wg * HIDN + lane] = hs_my;
    }
}

// ---------------------------------------------------------------------------
// k_probs: per (b,t): h1 = relu([hf,hb] @ bc_W1.T + b1); p = sig(h1.bc_W2+b2);
//          edge *1.2; clip [0,1].
// ---------------------------------------------------------------------------
__global__ __launch_bounds__(256) void k_probs(
    const float* __restrict__ hbuf,            // [2][B][L][32] fp32
    const float* __restrict__ bcW1, const float* __restrict__ bcb1,
    const float* __restrict__ bcW2, const float* __restrict__ bcb2,
    float* __restrict__ out)
{
    int idx = blockIdx.x * 256 + threadIdx.x;   // b*L + t
    int t = idx & (LSEQ - 1);
    int b = idx >> 14;

    float h[64];
    const float* pf = hbuf + (((size_t)b * LSEQ + t) << 5);
    const float* pb = hbuf + (((size_t)(BATCH + b) * LSEQ + t) << 5);
    #pragma unroll
    for (int q = 0; q < 8; ++q) {
        float4 v = reinterpret_cast<const float4*>(pf)[q];
        h[q * 4] = v.x; h[q * 4 + 1] = v.y; h[q * 4 + 2] = v.z; h[q * 4 + 3] = v.w;
    }
    #pragma unroll
    for (int q = 0; q < 8; ++q) {
        float4 v = reinterpret_cast<const float4*>(pb)[q];
        h[32 + q * 4] = v.x; h[32 + q * 4 + 1] = v.y; h[32 + q * 4 + 2] = v.z; h[32 + q * 4 + 3] = v.w;
    }

    float acc2 = (double)0.0 + bcb2[0];  // keep simple fp32 start
    double a2 = (double)bcb2[0];
    #pragma unroll 1
    for (int m = 0; m < 32; ++m) {
        double a = (double)bcb1[m];
        #pragma unroll
        for (int kk = 0; kk < 64; ++kk)
            a += (double)bcW1[m * 64 + kk] * (double)h[kk];
        float af = fmaxf((float)a, 0.f);
        a2 += (double)bcW2[m] * (double)af;
    }
    (void)acc2;
    float p = fsig((float)a2);
    if (t == 0 || t == LSEQ - 1) p = __fmul_rn(p, 1.2f);
    p = fminf(fmaxf(p, 0.f), 1.f);
    out[idx] = p;
}

__global__ __launch_bounds__(256) void k_adj(
    const float* __restrict__ probs, float* __restrict__ adj)
{
    int idx = blockIdx.x * 256 + threadIdx.x;
    int t = idx & (LSEQ - 1);
    float a = 0.f;
    if (t > 0 && t < LSEQ - 1) {
        float p = probs[idx], pm = probs[idx - 1], pp = probs[idx + 1];
        float left = __fadd_rn(p, -pm), right = __fadd_rn(p, -pp);
        float al = fabsf(left), ar = fabsf(right);
        if (left < 0.f && al > ar)       a = -1.f;
        else if (right < 0.f && ar > al) a =  1.f;
    }
    adj[idx] = a;
}

__global__ __launch_bounds__(64) void k_realp(
    const float* __restrict__ hsum, const float* __restrict__ rcW,
    const float* __restrict__ rcb, float* __restrict__ out)
{
    int b = threadIdx.x;
    if (b < BATCH) {
        const double invL = 1.0 / (double)LSEQ;
        double acc = (double)rcb[0];
        #pragma unroll
        for (int kk = 0; kk < 32; ++kk) {
            acc += (double)hsum[b * 32 + kk] * invL * (double)rcW[kk];
            acc += (double)hsum[(BATCH + b) * 32 + kk] * invL * (double)rcW[32 + kk];
        }
        out[b] = fsig((float)acc);
    }
}

// ---------------------------------------------------------------------------
extern "C" void kernel_launch(void* const* d_in, const int* in_sizes, int n_in,
                              void* d_out, int out_size, void* d_ws, size_t ws_size,
                              hipStream_t stream)
{
    (void)in_sizes; (void)n_in; (void)out_size;
    const float* features = (const float*)d_in[0];
    const float* proj_W   = (const float*)d_in[1];
    const float* proj_b   = (const float*)d_in[2];
    const float* Wih_f    = (const float*)d_in[3];
    const float* Whh_f    = (const float*)d_in[4];
    const float* bih_f    = (const float*)d_in[5];
    const float* bhh_f    = (const float*)d_in[6];
    const float* Wih_b    = (const float*)d_in[7];
    const float* Whh_b    = (const float*)d_in[8];
    const float* bih_b    = (const float*)d_in[9];
    const float* bhh_b    = (const float*)d_in[10];
    const float* bcW1     = (const float*)d_in[11];
    const float* bcb1     = (const float*)d_in[12];
    const float* bcW2     = (const float*)d_in[13];
    const float* bcb2     = (const float*)d_in[14];
    const float* rcW      = (const float*)d_in[15];
    const float* rcb      = (const float*)d_in[16];

    char* ws = (char*)d_ws;
    float* bias2 = (float*)(ws + 65536);       // 1 KiB
    float* hsum  = (float*)(ws + 66560);       // 8 KiB
    float* state = (float*)(ws + 74752);       // 16 KiB
    const size_t HBYTES = (size_t)2 * BATCH * LSEQ * HIDN * sizeof(float); // 128 MiB
    float* hbuf  = (float*)(ws + (1u << 20));
    float* gxbuf = (float*)(ws + (1u << 20) + HBYTES);
    const size_t GXOFF = (1u << 20) + HBYTES;

    // deterministic chunk choice from ws_size (Gx chunk = 32768*chunkT bytes)
    int chunkT = LSEQ;
    for (;;) {
        size_t need = GXOFF + (size_t)2 * BATCH * (size_t)chunkT * NGATE * 4 + 2048;
        if (need <= ws_size || chunkT <= 256) break;
        chunkT >>= 1;
    }
    const int nch = LSEQ / chunkT;

    float* outp = (float*)d_out;
    const int BL = BATCH * LSEQ;

    k_prep<<<16, 256, 0, stream>>>(bih_f, bhh_f, bih_b, bhh_b, bias2, hsum, state);
    for (int c = 0; c < nch; ++c) {
        int s0 = c * chunkT;
        k_gx<<<BATCH * (chunkT >> 8), 256, 0, stream>>>(features, proj_W, proj_b,
                                                        Wih_f, Wih_b, bias2, gxbuf, chunkT, s0);
        k_rec<<<64, 64, 0, stream>>>(gxbuf, Whh_f, Whh_b, hbuf, state, hsum, chunkT, s0);
    }
    k_probs<<<BL / 256, 256, 0, stream>>>(hbuf, bcW1, bcb1, bcW2, bcb2, outp);
    k_adj<<<BL / 256, 256, 0, stream>>>(outp, outp + BL);
    k_realp<<<1, 64, 0, stream>>>(hsum, rcW, rcb, outp + 2 * BL);
}

// Round 4
// 10630.403 us; speedup vs baseline: 1.1412x; 1.1412x over previous
//
#include <hip/hip_runtime.h>
#include <hip/hip_bf16.h>
#include <stdint.h>

#define LSEQ   16384
#define BATCH  32
#define HIDN   32
#define NGATE  128   // 4*HIDN
#define INDIM  64

// libm-accurate sigmoid (OCML expf, IEEE division)
__device__ __forceinline__ float fsig(float x) { return 1.f / (1.f + expf(-x)); }

__device__ __forceinline__ float readlane_f(float v, int l) {
    return __uint_as_float((unsigned)__builtin_amdgcn_readlane((int)__float_as_uint(v), l));
}

// ---------------------------------------------------------------------------
// k_prep: bias2[d][j] = bih[j] + bhh[j]; zero hsum (fp64) and h/c state.
// ---------------------------------------------------------------------------
__global__ __launch_bounds__(256) void k_prep(
    const float* __restrict__ bih_f, const float* __restrict__ bhh_f,
    const float* __restrict__ bih_b, const float* __restrict__ bhh_b,
    float* __restrict__ bias2, double* __restrict__ hsum, float* __restrict__ state)
{
    int gid = blockIdx.x * 256 + threadIdx.x;   // [0, 4096)
    if (gid < 256) {
        int dd = gid >> 7, jj = gid & 127;
        float bi = dd ? bih_b[jj] : bih_f[jj];
        float bh = dd ? bhh_b[jj] : bhh_f[jj];
        bias2[gid] = __fadd_rn(bi, bh);
    }
    if (gid < 2 * BATCH * HIDN) hsum[gid] = 0.0;
    state[gid] = 0.f;   // 4096 = 2*B*2*32
}

// ---------------------------------------------------------------------------
// k_gx: exact (fp64) dots rounded to fp32 where numpy rounds:
//   proj[m] = round_f32( proj_b[m] + sum_k proj_W[m,k]*f[k] )
//   gx[j]   = round_f32( (bih+bhh)[j] + sum_m Wih[j,m]*proj[m] )
// fp64 chains split into 4 accumulators (reassoc noise ~2^-52, harmless).
// ---------------------------------------------------------------------------
__global__ __launch_bounds__(256) void k_gx(
    const float* __restrict__ features,  // [B][64][L]
    const float* __restrict__ proj_W,    // [32][64]
    const float* __restrict__ proj_b,    // [32]
    const float* __restrict__ Wih_f,     // [128][32]
    const float* __restrict__ Wih_b,
    const float* __restrict__ bias2,     // [2][128]
    float* __restrict__ gx,
    int chunkT, int s0)
{
    int tilesPerB = chunkT >> 8;
    int b  = blockIdx.x / tilesPerB;
    int tt = (blockIdx.x % tilesPerB) * 256 + threadIdx.x;
    int s  = s0 + tt;

    #pragma unroll 1
    for (int d = 0; d < 2; ++d) {
        int t = d ? (LSEQ - 1 - s) : s;
        float f[INDIM];
        #pragma unroll
        for (int k = 0; k < INDIM; ++k)
            f[k] = features[((size_t)b * INDIM + k) * LSEQ + t];

        float proj[HIDN];
        #pragma unroll 1
        for (int m = 0; m < HIDN; ++m) {
            double sA = 0.0, sB = 0.0, sC = 0.0, sD = 0.0;
            #pragma unroll
            for (int k = 0; k < INDIM; k += 4) {
                sA += (double)proj_W[m * INDIM + k + 0] * (double)f[k + 0];
                sB += (double)proj_W[m * INDIM + k + 1] * (double)f[k + 1];
                sC += (double)proj_W[m * INDIM + k + 2] * (double)f[k + 2];
                sD += (double)proj_W[m * INDIM + k + 3] * (double)f[k + 3];
            }
            proj[m] = (float)(((double)proj_b[m] + sA + sB) + (sC + sD));
        }

        const float* Wih = d ? Wih_b : Wih_f;
        const float* bs  = bias2 + d * NGATE;
        float* out = gx + (((size_t)(d * BATCH + b) * chunkT + tt) << 7);
        #pragma unroll 1
        for (int j = 0; j < NGATE; j += 2) {
            double a0e = 0.0, a0o = 0.0, a1e = 0.0, a1o = 0.0;
            #pragma unroll
            for (int m = 0; m < HIDN; m += 2) {
                double pe = (double)proj[m], po = (double)proj[m + 1];
                a0e += (double)Wih[(j + 0) * HIDN + m]     * pe;
                a0o += (double)Wih[(j + 0) * HIDN + m + 1] * po;
                a1e += (double)Wih[(j + 1) * HIDN + m]     * pe;
                a1o += (double)Wih[(j + 1) * HIDN + m + 1] * po;
            }
            out[j]     = (float)(((double)bs[j]     + a0e) + a0o);
            out[j + 1] = (float)(((double)bs[j + 1] + a1e) + a1o);
        }
    }
}

// ---------------------------------------------------------------------------
// k_rec: sequential LSTM, one single-wave workgroup per (dir, batch).
// No barriers (single wave). h broadcast via v_readlane (h in SGPRs).
// fp32 fma matvec (weights resident in 64 VGPRs). Activations: libm
// tanhf/expf + IEEE div; c/h with numpy's rounding pattern; hsum in fp64.
// Lane l<32 owns gate rows i[k],f[k]; lane l>=32 owns g[k],o[k] (k=l&31).
// ---------------------------------------------------------------------------
__global__ __launch_bounds__(64) void k_rec(
    const float* __restrict__ gx,      // [2][B][chunkT][128] (+pad)
    const float* __restrict__ Whh_f,   // [128][32]
    const float* __restrict__ Whh_b,
    float* __restrict__ hbuf,          // [2][B][L][32] fp32
    float* __restrict__ state,         // [2][B][2][32]  (h then c)
    double* __restrict__ hsum,         // [2][B][32] fp64
    int chunkT, int s0)
{
    const int wg   = blockIdx.x;        // d*32 + b
    const int d    = wg >> 5;
    const int lane = threadIdx.x;
    const int k    = lane & 31;
    const int half = lane >> 5;         // 0: i/f rows, 1: g/o rows
    const int r0   = k + (half << 6);   // i or g row
    const int r1   = r0 + 32;           // f or o row

    const float* whh = d ? Whh_b : Whh_f;
    float w0[HIDN], w1[HIDN];
    #pragma unroll
    for (int m = 0; m < HIDN; ++m) {
        w0[m] = whh[r0 * HIDN + m];
        w1[m] = whh[r1 * HIDN + m];
    }

    float* st = state + (wg << 6);
    // all lanes load (hi-lane values unused garbage; readlane only reads 0..31)
    float hcur = st[k];
    float c_my = st[HIDN + k];
    double hs_my = (lane < HIDN) ? hsum[wg * HIDN + lane] : 0.0;

    const float* gq = gx + (((size_t)wg * chunkT) << 7);
    // prefetch pipeline depth 3 (no barrier drains now -> stays in flight)
    float c0v = gq[r0],       c1v = gq[r1];         // step tt
    float d0v = gq[128 + r0], d1v = gq[128 + r1];   // step tt+1
    float e0v = gq[256 + r0], e1v = gq[256 + r1];   // step tt+2

    const int t0 = d ? (LSEQ - 1 - s0) : s0;
    const int hinc = d ? -HIDN : HIDN;
    float* hp = hbuf + (((size_t)wg * LSEQ + t0) << 5) + k;

    for (int tt = 0; tt < chunkT; ++tt) {
        float g0 = c0v, g1 = c1v;
        c0v = d0v; c1v = d1v;
        d0v = e0v; d1v = e1v;
        e0v = gq[384 + r0]; e1v = gq[384 + r1];     // tt+3 (pad at tail)
        gq += NGATE;

        #pragma unroll
        for (int m = 0; m < HIDN; ++m) {
            float hm = readlane_f(hcur, m);         // SGPR operand
            g0 = fmaf(w0[m], hm, g0);
            g1 = fmaf(w1[m], hm, g1);
        }
        float a0 = half ? tanhf(g0) : fsig(g0);     // i (lo) / g (hi)
        float a1 = fsig(g1);                         // f (lo) / o (hi)
        float xg = __shfl_xor(a0, 32);               // lo lanes: tanh(g_k)
        float xo = __shfl_xor(a1, 32);               // lo lanes: sig(o_k)
        // numpy rounding pattern: c = (f*c) + (i*g); h = o * tanh(c)
        float p1 = __fmul_rn(a1, c_my);
        float p2 = __fmul_rn(a0, xg);
        float cn = __fadd_rn(p1, p2);
        float hn = __fmul_rn(xo, tanhf(cn));
        c_my = cn;
        hcur = hn;
        hs_my += (double)hn;
        if (lane < HIDN) *hp = hn;
        hp += hinc;
    }

    if (lane < HIDN) {
        st[lane] = hcur;
        st[HIDN + lane] = c_my;
        hsum[wg * HIDN + lane] = hs_my;
    }
}

// ---------------------------------------------------------------------------
// k_probs: per (b,t): h1 = relu([hf,hb] @ bc_W1.T + b1); p = sig(h1.bc_W2+b2);
//          edge *1.2; clip [0,1]. fp64 dots, 2-way chain split.
// ---------------------------------------------------------------------------
__global__ __launch_bounds__(256) void k_probs(
    const float* __restrict__ hbuf,            // [2][B][L][32] fp32
    const float* __restrict__ bcW1, const float* __restrict__ bcb1,
    const float* __restrict__ bcW2, const float* __restrict__ bcb2,
    float* __restrict__ out)
{
    int idx = blockIdx.x * 256 + threadIdx.x;   // b*L + t
    int t = idx & (LSEQ - 1);
    int b = idx >> 14;

    float h[64];
    const float* pf = hbuf + (((size_t)b * LSEQ + t) << 5);
    const float* pb = hbuf + (((size_t)(BATCH + b) * LSEQ + t) << 5);
    #pragma unroll
    for (int q = 0; q < 8; ++q) {
        float4 v = reinterpret_cast<const float4*>(pf)[q];
        h[q * 4] = v.x; h[q * 4 + 1] = v.y; h[q * 4 + 2] = v.z; h[q * 4 + 3] = v.w;
    }
    #pragma unroll
    for (int q = 0; q < 8; ++q) {
        float4 v = reinterpret_cast<const float4*>(pb)[q];
        h[32 + q * 4] = v.x; h[32 + q * 4 + 1] = v.y; h[32 + q * 4 + 2] = v.z; h[32 + q * 4 + 3] = v.w;
    }

    double a2 = (double)bcb2[0];
    #pragma unroll 1
    for (int m = 0; m < 32; ++m) {
        double ae = 0.0, ao = 0.0;
        #pragma unroll
        for (int kk = 0; kk < 64; kk += 2) {
            ae += (double)bcW1[m * 64 + kk]     * (double)h[kk];
            ao += (double)bcW1[m * 64 + kk + 1] * (double)h[kk + 1];
        }
        float af = fmaxf((float)(((double)bcb1[m] + ae) + ao), 0.f);
        a2 += (double)bcW2[m] * (double)af;
    }
    float p = fsig((float)a2);
    if (t == 0 || t == LSEQ - 1) p = __fmul_rn(p, 1.2f);
    p = fminf(fmaxf(p, 0.f), 1.f);
    out[idx] = p;
}

__global__ __launch_bounds__(256) void k_adj(
    const float* __restrict__ probs, float* __restrict__ adj)
{
    int idx = blockIdx.x * 256 + threadIdx.x;
    int t = idx & (LSEQ - 1);
    float a = 0.f;
    if (t > 0 && t < LSEQ - 1) {
        float p = probs[idx], pm = probs[idx - 1], pp = probs[idx + 1];
        float left = __fadd_rn(p, -pm), right = __fadd_rn(p, -pp);
        float al = fabsf(left), ar = fabsf(right);
        if (left < 0.f && al > ar)       a = -1.f;
        else if (right < 0.f && ar > al) a =  1.f;
    }
    adj[idx] = a;
}

__global__ __launch_bounds__(64) void k_realp(
    const double* __restrict__ hsum, const float* __restrict__ rcW,
    const float* __restrict__ rcb, float* __restrict__ out)
{
    int b = threadIdx.x;
    if (b < BATCH) {
        const double invL = 1.0 / (double)LSEQ;
        double acc = (double)rcb[0];
        #pragma unroll
        for (int kk = 0; kk < 32; ++kk) {
            acc += hsum[b * 32 + kk] * invL * (double)rcW[kk];
            acc += hsum[(BATCH + b) * 32 + kk] * invL * (double)rcW[32 + kk];
        }
        out[b] = fsig((float)acc);
    }
}

// ---------------------------------------------------------------------------
extern "C" void kernel_launch(void* const* d_in, const int* in_sizes, int n_in,
                              void* d_out, int out_size, void* d_ws, size_t ws_size,
                              hipStream_t stream)
{
    (void)in_sizes; (void)n_in; (void)out_size;
    const float* features = (const float*)d_in[0];
    const float* proj_W   = (const float*)d_in[1];
    const float* proj_b   = (const float*)d_in[2];
    const float* Wih_f    = (const float*)d_in[3];
    const float* Whh_f    = (const float*)d_in[4];
    const float* bih_f    = (const float*)d_in[5];
    const float* bhh_f    = (const float*)d_in[6];
    const float* Wih_b    = (const float*)d_in[7];
    const float* Whh_b    = (const float*)d_in[8];
    const float* bih_b    = (const float*)d_in[9];
    const float* bhh_b    = (const float*)d_in[10];
    const float* bcW1     = (const float*)d_in[11];
    const float* bcb1     = (const float*)d_in[12];
    const float* bcW2     = (const float*)d_in[13];
    const float* bcb2     = (const float*)d_in[14];
    const float* rcW      = (const float*)d_in[15];
    const float* rcb      = (const float*)d_in[16];

    char* ws = (char*)d_ws;
    float*  bias2 = (float*)(ws + 65536);              // 1 KiB
    double* hsum  = (double*)(ws + 66560);             // 16 KiB (fp64)
    float*  state = (float*)(ws + 82944);              // 16 KiB
    const size_t HBYTES = (size_t)2 * BATCH * LSEQ * HIDN * sizeof(float); // 128 MiB
    float* hbuf  = (float*)(ws + (1u << 20));
    float* gxbuf = (float*)(ws + (1u << 20) + HBYTES);
    const size_t GXOFF = (1u << 20) + HBYTES;

    // deterministic chunk choice from ws_size (Gx chunk = 32768*chunkT bytes)
    int chunkT = LSEQ;
    for (;;) {
        size_t need = GXOFF + (size_t)2 * BATCH * (size_t)chunkT * NGATE * 4 + 4096;
        if (need <= ws_size || chunkT <= 256) break;
        chunkT >>= 1;
    }
    const int nch = LSEQ / chunkT;

    float* outp = (float*)d_out;
    const int BL = BATCH * LSEQ;

    k_prep<<<16, 256, 0, stream>>>(bih_f, bhh_f, bih_b, bhh_b, bias2, hsum, state);
    for (int c = 0; c < nch; ++c) {
        int s0 = c * chunkT;
        k_gx<<<BATCH * (chunkT >> 8), 256, 0, stream>>>(features, proj_W, proj_b,
                                                        Wih_f, Wih_b, bias2, gxbuf, chunkT, s0);
        k_rec<<<64, 64, 0, stream>>>(gxbuf, Whh_f, Whh_b, hbuf, state, hsum, chunkT, s0);
    }
    k_probs<<<BL / 256, 256, 0, stream>>>(hbuf, bcW1, bcb1, bcW2, bcb2, outp);
    k_adj<<<BL / 256, 256, 0, stream>>>(outp, outp + BL);
    k_realp<<<1, 64, 0, stream>>>(hsum, rcW, rcb, outp + 2 * BL);
}

// Round 6
// 9345.864 us; speedup vs baseline: 1.2980x; 1.1374x over previous
//
#include <hip/hip_runtime.h>
#include <hip/hip_bf16.h>
#include <stdint.h>

#define LSEQ   16384
#define BATCH  32
#define HIDN   32
#define NGATE  128   // 4*HIDN
#define INDIM  64

// libm-accurate sigmoid (OCML expf, IEEE division) — accuracy required:
// fast exp2+rcp activations flip adj decisions (R5 fail).
__device__ __forceinline__ float fsig(float x) { return 1.f / (1.f + expf(-x)); }

__device__ __forceinline__ float readlane_f(float v, int l) {
    return __uint_as_float((unsigned)__builtin_amdgcn_readlane((int)__float_as_uint(v), l));
}

// ---------------------------------------------------------------------------
// k_prep: bias2[d][j] = bih[j] + bhh[j]; zero hsum (fp64) and h/c state.
// ---------------------------------------------------------------------------
__global__ __launch_bounds__(256) void k_prep(
    const float* __restrict__ bih_f, const float* __restrict__ bhh_f,
    const float* __restrict__ bih_b, const float* __restrict__ bhh_b,
    float* __restrict__ bias2, double* __restrict__ hsum, float* __restrict__ state)
{
    int gid = blockIdx.x * 256 + threadIdx.x;   // [0, 4096)
    if (gid < 256) {
        int dd = gid >> 7, jj = gid & 127;
        float bi = dd ? bih_b[jj] : bih_f[jj];
        float bh = dd ? bhh_b[jj] : bhh_f[jj];
        bias2[gid] = __fadd_rn(bi, bh);
    }
    if (gid < 2 * BATCH * HIDN) hsum[gid] = 0.0;
    state[gid] = 0.f;   // 4096 = 2*B*2*32
}

// ---------------------------------------------------------------------------
// k_gx: exact (fp64) dots rounded to fp32 where numpy rounds:
//   proj[m] = round_f32( proj_b[m] + sum_k proj_W[m,k]*f[k] )
//   gx[j]   = round_f32( (bih+bhh)[j] + sum_m Wih[j,m]*proj[m] )
// ---------------------------------------------------------------------------
__global__ __launch_bounds__(256) void k_gx(
    const float* __restrict__ features,  // [B][64][L]
    const float* __restrict__ proj_W,    // [32][64]
    const float* __restrict__ proj_b,    // [32]
    const float* __restrict__ Wih_f,     // [128][32]
    const float* __restrict__ Wih_b,
    const float* __restrict__ bias2,     // [2][128]
    float* __restrict__ gx,
    int chunkT, int s0)
{
    int tilesPerB = chunkT >> 8;
    int b  = blockIdx.x / tilesPerB;
    int tt = (blockIdx.x % tilesPerB) * 256 + threadIdx.x;
    int s  = s0 + tt;

    #pragma unroll 1
    for (int d = 0; d < 2; ++d) {
        int t = d ? (LSEQ - 1 - s) : s;
        float f[INDIM];
        #pragma unroll
        for (int k = 0; k < INDIM; ++k)
            f[k] = features[((size_t)b * INDIM + k) * LSEQ + t];

        float proj[HIDN];
        #pragma unroll 1
        for (int m = 0; m < HIDN; ++m) {
            double sA = 0.0, sB = 0.0, sC = 0.0, sD = 0.0;
            #pragma unroll
            for (int k = 0; k < INDIM; k += 4) {
                sA += (double)proj_W[m * INDIM + k + 0] * (double)f[k + 0];
                sB += (double)proj_W[m * INDIM + k + 1] * (double)f[k + 1];
                sC += (double)proj_W[m * INDIM + k + 2] * (double)f[k + 2];
                sD += (double)proj_W[m * INDIM + k + 3] * (double)f[k + 3];
            }
            proj[m] = (float)(((double)proj_b[m] + sA + sB) + (sC + sD));
        }

        const float* Wih = d ? Wih_b : Wih_f;
        const float* bs  = bias2 + d * NGATE;
        float* out = gx + (((size_t)(d * BATCH + b) * chunkT + tt) << 7);
        #pragma unroll 1
        for (int j = 0; j < NGATE; j += 2) {
            double a0e = 0.0, a0o = 0.0, a1e = 0.0, a1o = 0.0;
            #pragma unroll
            for (int m = 0; m < HIDN; m += 2) {
                double pe = (double)proj[m], po = (double)proj[m + 1];
                a0e += (double)Wih[(j + 0) * HIDN + m]     * pe;
                a0o += (double)Wih[(j + 0) * HIDN + m + 1] * po;
                a1e += (double)Wih[(j + 1) * HIDN + m]     * pe;
                a1o += (double)Wih[(j + 1) * HIDN + m + 1] * po;
            }
            float2 o2;
            o2.x = (float)(((double)bs[j]     + a0e) + a0o);
            o2.y = (float)(((double)bs[j + 1] + a1e) + a1o);
            *reinterpret_cast<float2*>(out + j) = o2;
        }
    }
}

// ---------------------------------------------------------------------------
// k_rec: sequential LSTM, one single-wave workgroup per (dir, batch).
// Numerics bit-exact to the R4-passing version: libm tanhf/expf, IEEE div,
// sequential fma matvec, numpy c/h rounding. Structural: no barriers,
// v_readlane h-broadcast, depth-4 rotated gx prefetch, __launch_bounds__(64,1)
// + asm pins so the 64 weight VGPRs stay resident (R4: regalloc sank them).
// Lane l<32 owns gate rows i[k],f[k]; lane l>=32 owns g[k],o[k] (k=l&31).
// ---------------------------------------------------------------------------
__global__ __launch_bounds__(64, 1) void k_rec(
    const float* __restrict__ gx,      // [2][B][chunkT][128] (+pad)
    const float* __restrict__ Whh_f,   // [128][32]
    const float* __restrict__ Whh_b,
    float* __restrict__ hbuf,          // [2][B][L][32] fp32
    float* __restrict__ state,         // [2][B][2][32]  (h then c)
    double* __restrict__ hsum,         // [2][B][32] fp64
    int chunkT, int s0)
{
    const int wg   = blockIdx.x;        // d*32 + b
    const int d    = wg >> 5;
    const int lane = threadIdx.x;
    const int k    = lane & 31;
    const int half = lane >> 5;         // 0: i/f rows, 1: g/o rows
    const int r0   = k + (half << 6);   // i or g row
    const int r1   = r0 + 32;           // f or o row

    const float* whh = d ? Whh_b : Whh_f;
    float w0[HIDN], w1[HIDN];
    #pragma unroll
    for (int m = 0; m < HIDN; ++m) {
        w0[m] = whh[r0 * HIDN + m];
        w1[m] = whh[r1 * HIDN + m];
        // pin: force residency in VGPRs (prevents regalloc load-sinking)
        asm volatile("" : "+v"(w0[m]), "+v"(w1[m]));
    }

    float* st = state + (wg << 6);
    float hcur = st[k];                 // hi lanes: garbage, never read back
    float c_my = st[HIDN + k];
    double hs_my = (lane < HIDN) ? hsum[wg * HIDN + lane] : 0.0;

    const float* gq = gx + (((size_t)wg * chunkT) << 7);
    // 4-deep prefetch, rotated by 4-step unroll
    float cur0[4], cur1[4], nxt0[4], nxt1[4];
    #pragma unroll
    for (int u = 0; u < 4; ++u) {
        cur0[u] = gq[u * 128 + r0];
        cur1[u] = gq[u * 128 + r1];
    }

    const int t0 = d ? (LSEQ - 1 - s0) : s0;
    const int hinc = d ? -HIDN : HIDN;
    float* hp = hbuf + (((size_t)wg * LSEQ + t0) << 5) + k;

    #pragma unroll 1
    for (int tt = 0; tt < chunkT; tt += 4) {
        #pragma unroll
        for (int u = 0; u < 4; ++u) {
            // prefetch row tt+u+4 (tail reads land in the 4 KiB pad)
            nxt0[u] = gq[(u + 4) * 128 + r0];
            nxt1[u] = gq[(u + 4) * 128 + r1];

            float g0 = cur0[u], g1 = cur1[u];
            #pragma unroll
            for (int m = 0; m < HIDN; ++m) {
                float hm = readlane_f(hcur, m);     // SGPR broadcast
                g0 = fmaf(w0[m], hm, g0);
                g1 = fmaf(w1[m], hm, g1);
            }
            float a0 = half ? tanhf(g0) : fsig(g0); // i (lo) / g (hi)
            float a1 = fsig(g1);                    // f (lo) / o (hi)
            float xg = __shfl_xor(a0, 32);          // lo lanes: tanh(g_k)
            float xo = __shfl_xor(a1, 32);          // lo lanes: sig(o_k)
            // c = (f*c) + (i*g); h = o * tanh(c)   (numpy rounding pattern)
            float p1 = __fmul_rn(a1, c_my);
            float p2 = __fmul_rn(a0, xg);
            float cn = __fadd_rn(p1, p2);
            float hn = __fmul_rn(xo, tanhf(cn));
            c_my = cn;
            hcur = hn;
            hs_my += (double)hn;
            if (lane < HIDN) *hp = hn;
            hp += hinc;
        }
        #pragma unroll
        for (int u = 0; u < 4; ++u) { cur0[u] = nxt0[u]; cur1[u] = nxt1[u]; }
        gq += 4 * NGATE;
    }

    if (lane < HIDN) {
        st[lane] = hcur;
        st[HIDN + lane] = c_my;
        hsum[wg * HIDN + lane] = hs_my;
    }
}

// ---------------------------------------------------------------------------
// k_probs: per (b,t): h1 = relu([hf,hb] @ bc_W1.T + b1); p = sig(h1.bc_W2+b2);
//          edge *1.2; clip [0,1]. fp64 dots, 2-way chain split.
// ---------------------------------------------------------------------------
__global__ __launch_bounds__(256) void k_probs(
    const float* __restrict__ hbuf,            // [2][B][L][32] fp32
    const float* __restrict__ bcW1, const float* __restrict__ bcb1,
    const float* __restrict__ bcW2, const float* __restrict__ bcb2,
    float* __restrict__ out)
{
    int idx = blockIdx.x * 256 + threadIdx.x;   // b*L + t
    int t = idx & (LSEQ - 1);
    int b = idx >> 14;

    float h[64];
    const float* pf = hbuf + (((size_t)b * LSEQ + t) << 5);
    const float* pb = hbuf + (((size_t)(BATCH + b) * LSEQ + t) << 5);
    #pragma unroll
    for (int q = 0; q < 8; ++q) {
        float4 v = reinterpret_cast<const float4*>(pf)[q];
        h[q * 4] = v.x; h[q * 4 + 1] = v.y; h[q * 4 + 2] = v.z; h[q * 4 + 3] = v.w;
    }
    #pragma unroll
    for (int q = 0; q < 8; ++q) {
        float4 v = reinterpret_cast<const float4*>(pb)[q];
        h[32 + q * 4] = v.x; h[32 + q * 4 + 1] = v.y; h[32 + q * 4 + 2] = v.z; h[32 + q * 4 + 3] = v.w;
    }

    double a2 = (double)bcb2[0];
    #pragma unroll 1
    for (int m = 0; m < 32; ++m) {
        double ae = 0.0, ao = 0.0;
        #pragma unroll
        for (int kk = 0; kk < 64; kk += 2) {
            ae += (double)bcW1[m * 64 + kk]     * (double)h[kk];
            ao += (double)bcW1[m * 64 + kk + 1] * (double)h[kk + 1];
        }
        float af = fmaxf((float)(((double)bcb1[m] + ae) + ao), 0.f);
        a2 += (double)bcW2[m] * (double)af;
    }
    float p = fsig((float)a2);
    if (t == 0 || t == LSEQ - 1) p = __fmul_rn(p, 1.2f);
    p = fminf(fmaxf(p, 0.f), 1.f);
    out[idx] = p;
}

__global__ __launch_bounds__(256) void k_adj(
    const float* __restrict__ probs, float* __restrict__ adj)
{
    int idx = blockIdx.x * 256 + threadIdx.x;
    int t = idx & (LSEQ - 1);
    float a = 0.f;
    if (t > 0 && t < LSEQ - 1) {
        float p = probs[idx], pm = probs[idx - 1], pp = probs[idx + 1];
        float left = __fadd_rn(p, -pm), right = __fadd_rn(p, -pp);
        float al = fabsf(left), ar = fabsf(right);
        if (left < 0.f && al > ar)       a = -1.f;
        else if (right < 0.f && ar > al) a =  1.f;
    }
    adj[idx] = a;
}

__global__ __launch_bounds__(64) void k_realp(
    const double* __restrict__ hsum, const float* __restrict__ rcW,
    const float* __restrict__ rcb, float* __restrict__ out)
{
    int b = threadIdx.x;
    if (b < BATCH) {
        const double invL = 1.0 / (double)LSEQ;
        double acc = (double)rcb[0];
        #pragma unroll
        for (int kk = 0; kk < 32; ++kk) {
            acc += hsum[b * 32 + kk] * invL * (double)rcW[kk];
            acc += hsum[(BATCH + b) * 32 + kk] * invL * (double)rcW[32 + kk];
        }
        out[b] = fsig((float)acc);
    }
}

// ---------------------------------------------------------------------------
extern "C" void kernel_launch(void* const* d_in, const int* in_sizes, int n_in,
                              void* d_out, int out_size, void* d_ws, size_t ws_size,
                              hipStream_t stream)
{
    (void)in_sizes; (void)n_in; (void)out_size;
    const float* features = (const float*)d_in[0];
    const float* proj_W   = (const float*)d_in[1];
    const float* proj_b   = (const float*)d_in[2];
    const float* Wih_f    = (const float*)d_in[3];
    const float* Whh_f    = (const float*)d_in[4];
    const float* bih_f    = (const float*)d_in[5];
    const float* bhh_f    = (const float*)d_in[6];
    const float* Wih_b    = (const float*)d_in[7];
    const float* Whh_b    = (const float*)d_in[8];
    const float* bih_b    = (const float*)d_in[9];
    const float* bhh_b    = (const float*)d_in[10];
    const float* bcW1     = (const float*)d_in[11];
    const float* bcb1     = (const float*)d_in[12];
    const float* bcW2     = (const float*)d_in[13];
    const float* bcb2     = (const float*)d_in[14];
    const float* rcW      = (const float*)d_in[15];
    const float* rcb      = (const float*)d_in[16];

    char* ws = (char*)d_ws;
    float*  bias2 = (float*)(ws + 65536);              // 1 KiB
    double* hsum  = (double*)(ws + 66560);             // 16 KiB (fp64)
    float*  state = (float*)(ws + 82944);              // 16 KiB
    const size_t HBYTES = (size_t)2 * BATCH * LSEQ * HIDN * sizeof(float); // 128 MiB
    float* hbuf  = (float*)(ws + (1u << 20));
    float* gxbuf = (float*)(ws + (1u << 20) + HBYTES);
    const size_t GXOFF = (1u << 20) + HBYTES;

    // deterministic chunk choice from ws_size; cap at 4096 so the gx chunk
    // stays L3-resident between k_gx and k_rec
    int chunkT = 4096;
    for (;;) {
        size_t need = GXOFF + (size_t)2 * BATCH * (size_t)chunkT * NGATE * 4 + 4096;
        if (need <= ws_size || chunkT <= 256) break;
        chunkT >>= 1;
    }
    const int nch = LSEQ / chunkT;

    float* outp = (float*)d_out;
    const int BL = BATCH * LSEQ;

    k_prep<<<16, 256, 0, stream>>>(bih_f, bhh_f, bih_b, bhh_b, bias2, hsum, state);
    for (int c = 0; c < nch; ++c) {
        int s0 = c * chunkT;
        k_gx<<<BATCH * (chunkT >> 8), 256, 0, stream>>>(features, proj_W, proj_b,
                                                        Wih_f, Wih_b, bias2, gxbuf, chunkT, s0);
        k_rec<<<64, 64, 0, stream>>>(gxbuf, Whh_f, Whh_b, hbuf, state, hsum, chunkT, s0);
    }
    k_probs<<<BL / 256, 256, 0, stream>>>(hbuf, bcW1, bcb1, bcW2, bcb2, outp);
    k_adj<<<BL / 256, 256, 0, stream>>>(outp, outp + BL);
    k_realp<<<1, 64, 0, stream>>>(hsum, rcW, rcb, outp + 2 * BL);
}

// Round 7
// 7908.168 us; speedup vs baseline: 1.5340x; 1.1818x over previous
//
#include <hip/hip_runtime.h>
#include <hip/hip_bf16.h>
#include <stdint.h>

#define LSEQ   16384
#define BATCH  32
#define HIDN   32
#define NGATE  128   // 4*HIDN
#define INDIM  64

// libm-accurate sigmoid for the small output kernels (accuracy matters there,
// cost doesn't: they're massively parallel one-shot dispatches).
__device__ __forceinline__ float fsig(float x) { return 1.f / (1.f + expf(-x)); }

__device__ __forceinline__ float readlane_f(float v, int l) {
    return __uint_as_float((unsigned)__builtin_amdgcn_readlane((int)__float_as_uint(v), l));
}

// ---------------------------------------------------------------------------
// k_prep: bias2[d][j] = bih[j] + bhh[j]; zero hsum (fp64) and h/c state.
// ---------------------------------------------------------------------------
__global__ __launch_bounds__(256) void k_prep(
    const float* __restrict__ bih_f, const float* __restrict__ bhh_f,
    const float* __restrict__ bih_b, const float* __restrict__ bhh_b,
    float* __restrict__ bias2, double* __restrict__ hsum, float* __restrict__ state)
{
    int gid = blockIdx.x * 256 + threadIdx.x;   // [0, 4096)
    if (gid < 256) {
        int dd = gid >> 7, jj = gid & 127;
        float bi = dd ? bih_b[jj] : bih_f[jj];
        float bh = dd ? bhh_b[jj] : bhh_f[jj];
        bias2[gid] = __fadd_rn(bi, bh);
    }
    if (gid < 2 * BATCH * HIDN) hsum[gid] = 0.0;
    state[gid] = 0.f;   // 4096 = 2*B*2*32
}

// ---------------------------------------------------------------------------
// k_gx: exact (fp64) dots rounded to fp32 where numpy rounds:
//   proj[m] = round_f32( proj_b[m] + sum_k proj_W[m,k]*f[k] )
//   gx[j]   = round_f32( (bih+bhh)[j] + sum_m Wih[j,m]*proj[m] )
// ---------------------------------------------------------------------------
__global__ __launch_bounds__(256) void k_gx(
    const float* __restrict__ features,  // [B][64][L]
    const float* __restrict__ proj_W,    // [32][64]
    const float* __restrict__ proj_b,    // [32]
    const float* __restrict__ Wih_f,     // [128][32]
    const float* __restrict__ Wih_b,
    const float* __restrict__ bias2,     // [2][128]
    float* __restrict__ gx,
    int chunkT, int s0)
{
    int tilesPerB = chunkT >> 8;
    int b  = blockIdx.x / tilesPerB;
    int tt = (blockIdx.x % tilesPerB) * 256 + threadIdx.x;
    int s  = s0 + tt;

    #pragma unroll 1
    for (int d = 0; d < 2; ++d) {
        int t = d ? (LSEQ - 1 - s) : s;
        float f[INDIM];
        #pragma unroll
        for (int k = 0; k < INDIM; ++k)
            f[k] = features[((size_t)b * INDIM + k) * LSEQ + t];

        float proj[HIDN];
        #pragma unroll 1
        for (int m = 0; m < HIDN; ++m) {
            double sA = 0.0, sB = 0.0, sC = 0.0, sD = 0.0;
            #pragma unroll
            for (int k = 0; k < INDIM; k += 4) {
                sA += (double)proj_W[m * INDIM + k + 0] * (double)f[k + 0];
                sB += (double)proj_W[m * INDIM + k + 1] * (double)f[k + 1];
                sC += (double)proj_W[m * INDIM + k + 2] * (double)f[k + 2];
                sD += (double)proj_W[m * INDIM + k + 3] * (double)f[k + 3];
            }
            proj[m] = (float)(((double)proj_b[m] + sA + sB) + (sC + sD));
        }

        const float* Wih = d ? Wih_b : Wih_f;
        const float* bs  = bias2 + d * NGATE;
        float* out = gx + (((size_t)(d * BATCH + b) * chunkT + tt) << 7);
        #pragma unroll 1
        for (int j = 0; j < NGATE; j += 2) {
            double a0e = 0.0, a0o = 0.0, a1e = 0.0, a1o = 0.0;
            #pragma unroll
            for (int m = 0; m < HIDN; m += 2) {
                double pe = (double)proj[m], po = (double)proj[m + 1];
                a0e += (double)Wih[(j + 0) * HIDN + m]     * pe;
                a0o += (double)Wih[(j + 0) * HIDN + m + 1] * po;
                a1e += (double)Wih[(j + 1) * HIDN + m]     * pe;
                a1o += (double)Wih[(j + 1) * HIDN + m + 1] * po;
            }
            float2 o2;
            o2.x = (float)(((double)bs[j]     + a0e) + a0o);
            o2.y = (float)(((double)bs[j + 1] + a1e) + a1o);
            *reinterpret_cast<float2*>(out + j) = o2;
        }
    }
}

// ---------------------------------------------------------------------------
// k_rec: sequential LSTM, one single-wave workgroup per (dir, batch).
// No barriers, NO libm calls: all activations via __expf (v_mul+v_exp) +
// IEEE division (correctly rounded — R5 showed biased rcp is fatal):
//   sigmoid(x) = 1/(1+e^{-x});  tanh(x) = 2/(1+e^{-2x}) - 1
// unified branch-free: a = num/(1+__expf(q*x)) + add, per-lane (num,q,add).
// Lane l<32 owns gate rows i[k],f[k]; lane l>=32 owns g[k],o[k] (k=l&31).
// ---------------------------------------------------------------------------
__global__ __launch_bounds__(64, 1) void k_rec(
    const float* __restrict__ gx,      // [2][B][chunkT][128] (+pad)
    const float* __restrict__ Whh_f,   // [128][32]
    const float* __restrict__ Whh_b,
    float* __restrict__ hbuf,          // [2][B][L][32] fp32
    float* __restrict__ state,         // [2][B][2][32]  (h then c)
    double* __restrict__ hsum,         // [2][B][32] fp64
    int chunkT, int s0)
{
    const int wg   = blockIdx.x;        // d*32 + b
    const int d    = wg >> 5;
    const int lane = threadIdx.x;
    const int k    = lane & 31;
    const int half = lane >> 5;         // 0: i/f rows, 1: g/o rows
    const int r0   = k + (half << 6);   // i or g row
    const int r1   = r0 + 32;           // f or o row

    // a0 activation: lo lanes sigmoid(i), hi lanes tanh(g)
    const float qA   = half ? -2.f : -1.f;
    const float numA = half ?  2.f :  1.f;
    const float addA = half ? -1.f :  0.f;

    const float* whh = d ? Whh_b : Whh_f;
    float w0[HIDN], w1[HIDN];
    #pragma unroll
    for (int m = 0; m < HIDN; ++m) {
        w0[m] = whh[r0 * HIDN + m];
        w1[m] = whh[r1 * HIDN + m];
        asm volatile("" : "+v"(w0[m]), "+v"(w1[m]));   // keep resident
    }

    float* st = state + (wg << 6);
    float hcur = st[k];                 // hi lanes: garbage, never read back
    float c_my = st[HIDN + k];
    double hs_my = (lane < HIDN) ? hsum[wg * HIDN + lane] : 0.0;

    const float* gq = gx + (((size_t)wg * chunkT) << 7);
    // 4-deep prefetch, rotated by 4-step unroll
    float cur0[4], cur1[4], nxt0[4], nxt1[4];
    #pragma unroll
    for (int u = 0; u < 4; ++u) {
        cur0[u] = gq[u * 128 + r0];
        cur1[u] = gq[u * 128 + r1];
    }

    const int t0 = d ? (LSEQ - 1 - s0) : s0;
    const int hinc = d ? -HIDN : HIDN;
    float* hp = hbuf + (((size_t)wg * LSEQ + t0) << 5) + k;

    #pragma unroll 1
    for (int tt = 0; tt < chunkT; tt += 4) {
        #pragma unroll
        for (int u = 0; u < 4; ++u) {
            // prefetch row tt+u+4 (tail reads land in the 4 KiB pad)
            nxt0[u] = gq[(u + 4) * 128 + r0];
            nxt1[u] = gq[(u + 4) * 128 + r1];

            float g0 = cur0[u], g1 = cur1[u];
            #pragma unroll
            for (int m = 0; m < HIDN; ++m) {
                float hm = readlane_f(hcur, m);     // SGPR broadcast
                g0 = fmaf(w0[m], hm, g0);
                g1 = fmaf(w1[m], hm, g1);
            }
            // a0 = sig(g0) lo | tanh(g0) hi   (branch-free, IEEE div)
            float e0 = __expf(qA * g0);
            float a0 = numA / (1.f + e0) + addA;
            // a1 = sig(g1): f (lo) / o (hi)
            float e1 = __expf(-g1);
            float a1 = 1.f / (1.f + e1);
            float xg = __shfl_xor(a0, 32);          // lo lanes: tanh(g_k)
            float xo = __shfl_xor(a1, 32);          // lo lanes: sig(o_k)
            // c = (f*c) + (i*g); h = o * tanh(c)   (numpy rounding pattern)
            float p1 = __fmul_rn(a1, c_my);
            float p2 = __fmul_rn(a0, xg);
            float cn = __fadd_rn(p1, p2);
            float ec = __expf(-2.f * cn);
            float tc = 2.f / (1.f + ec) - 1.f;      // tanh(c)
            float hn = __fmul_rn(xo, tc);
            c_my = cn;
            hcur = hn;
            hs_my += (double)hn;
            if (lane < HIDN) *hp = hn;
            hp += hinc;
        }
        #pragma unroll
        for (int u = 0; u < 4; ++u) { cur0[u] = nxt0[u]; cur1[u] = nxt1[u]; }
        gq += 4 * NGATE;
    }

    if (lane < HIDN) {
        st[lane] = hcur;
        st[HIDN + lane] = c_my;
        hsum[wg * HIDN + lane] = hs_my;
    }
}

// ---------------------------------------------------------------------------
// k_probs: per (b,t): h1 = relu([hf,hb] @ bc_W1.T + b1); p = sig(h1.bc_W2+b2);
//          edge *1.2; clip [0,1]. fp64 dots, 2-way chain split.
// ---------------------------------------------------------------------------
__global__ __launch_bounds__(256) void k_probs(
    const float* __restrict__ hbuf,            // [2][B][L][32] fp32
    const float* __restrict__ bcW1, const float* __restrict__ bcb1,
    const float* __restrict__ bcW2, const float* __restrict__ bcb2,
    float* __restrict__ out)
{
    int idx = blockIdx.x * 256 + threadIdx.x;   // b*L + t
    int t = idx & (LSEQ - 1);
    int b = idx >> 14;

    float h[64];
    const float* pf = hbuf + (((size_t)b * LSEQ + t) << 5);
    const float* pb = hbuf + (((size_t)(BATCH + b) * LSEQ + t) << 5);
    #pragma unroll
    for (int q = 0; q < 8; ++q) {
        float4 v = reinterpret_cast<const float4*>(pf)[q];
        h[q * 4] = v.x; h[q * 4 + 1] = v.y; h[q * 4 + 2] = v.z; h[q * 4 + 3] = v.w;
    }
    #pragma unroll
    for (int q = 0; q < 8; ++q) {
        float4 v = reinterpret_cast<const float4*>(pb)[q];
        h[32 + q * 4] = v.x; h[32 + q * 4 + 1] = v.y; h[32 + q * 4 + 2] = v.z; h[32 + q * 4 + 3] = v.w;
    }

    double a2 = (double)bcb2[0];
    #pragma unroll 1
    for (int m = 0; m < 32; ++m) {
        double ae = 0.0, ao = 0.0;
        #pragma unroll
        for (int kk = 0; kk < 64; kk += 2) {
            ae += (double)bcW1[m * 64 + kk]     * (double)h[kk];
            ao += (double)bcW1[m * 64 + kk + 1] * (double)h[kk + 1];
        }
        float af = fmaxf((float)(((double)bcb1[m] + ae) + ao), 0.f);
        a2 += (double)bcW2[m] * (double)af;
    }
    float p = fsig((float)a2);
    if (t == 0 || t == LSEQ - 1) p = __fmul_rn(p, 1.2f);
    p = fminf(fmaxf(p, 0.f), 1.f);
    out[idx] = p;
}

__global__ __launch_bounds__(256) void k_adj(
    const float* __restrict__ probs, float* __restrict__ adj)
{
    int idx = blockIdx.x * 256 + threadIdx.x;
    int t = idx & (LSEQ - 1);
    float a = 0.f;
    if (t > 0 && t < LSEQ - 1) {
        float p = probs[idx], pm = probs[idx - 1], pp = probs[idx + 1];
        float left = __fadd_rn(p, -pm), right = __fadd_rn(p, -pp);
        float al = fabsf(left), ar = fabsf(right);
        if (left < 0.f && al > ar)       a = -1.f;
        else if (right < 0.f && ar > al) a =  1.f;
    }
    adj[idx] = a;
}

__global__ __launch_bounds__(64) void k_realp(
    const double* __restrict__ hsum, const float* __restrict__ rcW,
    const float* __restrict__ rcb, float* __restrict__ out)
{
    int b = threadIdx.x;
    if (b < BATCH) {
        const double invL = 1.0 / (double)LSEQ;
        double acc = (double)rcb[0];
        #pragma unroll
        for (int kk = 0; kk < 32; ++kk) {
            acc += hsum[b * 32 + kk] * invL * (double)rcW[kk];
            acc += hsum[(BATCH + b) * 32 + kk] * invL * (double)rcW[32 + kk];
        }
        out[b] = fsig((float)acc);
    }
}

// ---------------------------------------------------------------------------
extern "C" void kernel_launch(void* const* d_in, const int* in_sizes, int n_in,
                              void* d_out, int out_size, void* d_ws, size_t ws_size,
                              hipStream_t stream)
{
    (void)in_sizes; (void)n_in; (void)out_size;
    const float* features = (const float*)d_in[0];
    const float* proj_W   = (const float*)d_in[1];
    const float* proj_b   = (const float*)d_in[2];
    const float* Wih_f    = (const float*)d_in[3];
    const float* Whh_f    = (const float*)d_in[4];
    const float* bih_f    = (const float*)d_in[5];
    const float* bhh_f    = (const float*)d_in[6];
    const float* Wih_b    = (const float*)d_in[7];
    const float* Whh_b    = (const float*)d_in[8];
    const float* bih_b    = (const float*)d_in[9];
    const float* bhh_b    = (const float*)d_in[10];
    const float* bcW1     = (const float*)d_in[11];
    const float* bcb1     = (const float*)d_in[12];
    const float* bcW2     = (const float*)d_in[13];
    const float* bcb2     = (const float*)d_in[14];
    const float* rcW      = (const float*)d_in[15];
    const float* rcb      = (const float*)d_in[16];

    char* ws = (char*)d_ws;
    float*  bias2 = (float*)(ws + 65536);              // 1 KiB
    double* hsum  = (double*)(ws + 66560);             // 16 KiB (fp64)
    float*  state = (float*)(ws + 82944);              // 16 KiB
    const size_t HBYTES = (size_t)2 * BATCH * LSEQ * HIDN * sizeof(float); // 128 MiB
    float* hbuf  = (float*)(ws + (1u << 20));
    float* gxbuf = (float*)(ws + (1u << 20) + HBYTES);
    const size_t GXOFF = (1u << 20) + HBYTES;

    // deterministic chunk choice from ws_size; cap at 4096 so the gx chunk
    // stays L3-resident between k_gx and k_rec
    int chunkT = 4096;
    for (;;) {
        size_t need = GXOFF + (size_t)2 * BATCH * (size_t)chunkT * NGATE * 4 + 4096;
        if (need <= ws_size || chunkT <= 256) break;
        chunkT >>= 1;
    }
    const int nch = LSEQ / chunkT;

    float* outp = (float*)d_out;
    const int BL = BATCH * LSEQ;

    k_prep<<<16, 256, 0, stream>>>(bih_f, bhh_f, bih_b, bhh_b, bias2, hsum, state);
    for (int c = 0; c < nch; ++c) {
        int s0 = c * chunkT;
        k_gx<<<BATCH * (chunkT >> 8), 256, 0, stream>>>(features, proj_W, proj_b,
                                                        Wih_f, Wih_b, bias2, gxbuf, chunkT, s0);
        k_rec<<<64, 64, 0, stream>>>(gxbuf, Whh_f, Whh_b, hbuf, state, hsum, chunkT, s0);
    }
    k_probs<<<BL / 256, 256, 0, stream>>>(hbuf, bcW1, bcb1, bcW2, bcb2, outp);
    k_adj<<<BL / 256, 256, 0, stream>>>(outp, outp + BL);
    k_realp<<<1, 64, 0, stream>>>(hsum, rcW, rcb, outp + 2 * BL);
}

// Round 8
// 7499.916 us; speedup vs baseline: 1.6175x; 1.0544x over previous
//
#include <hip/hip_runtime.h>
#include <hip/hip_bf16.h>
#include <stdint.h>

#define LSEQ   16384
#define BATCH  32
#define HIDN   32
#define NGATE  128   // 4*HIDN
#define INDIM  64

typedef float v2f __attribute__((ext_vector_type(2)));

// libm-accurate sigmoid for the small output kernels.
__device__ __forceinline__ float fsig(float x) { return 1.f / (1.f + expf(-x)); }

__device__ __forceinline__ float readlane_f(float v, int l) {
    return __uint_as_float((unsigned)__builtin_amdgcn_readlane((int)__float_as_uint(v), l));
}

// ---------------------------------------------------------------------------
// k_prep: bias2[d][j] = bih[j] + bhh[j]; zero hsum (fp64) and h/c state.
// ---------------------------------------------------------------------------
__global__ __launch_bounds__(256) void k_prep(
    const float* __restrict__ bih_f, const float* __restrict__ bhh_f,
    const float* __restrict__ bih_b, const float* __restrict__ bhh_b,
    float* __restrict__ bias2, double* __restrict__ hsum, float* __restrict__ state)
{
    int gid = blockIdx.x * 256 + threadIdx.x;   // [0, 4096)
    if (gid < 256) {
        int dd = gid >> 7, jj = gid & 127;
        float bi = dd ? bih_b[jj] : bih_f[jj];
        float bh = dd ? bhh_b[jj] : bhh_f[jj];
        bias2[gid] = __fadd_rn(bi, bh);
    }
    if (gid < 2 * BATCH * HIDN) hsum[gid] = 0.0;
    state[gid] = 0.f;   // 4096 = 2*B*2*32
}

// ---------------------------------------------------------------------------
// k_gx: exact (fp64) dots rounded to fp32 where numpy rounds (bitwise same
// values as the R7-passing version; only the STORE LAYOUT changed):
//   out2[k]    = (i_k, f_k)     k in [0,32)
//   out2[32+k] = (g_k, o_k)
// so k_rec lane l reads one coalesced float2 at out2[l].
// ---------------------------------------------------------------------------
__global__ __launch_bounds__(256) void k_gx(
    const float* __restrict__ features,  // [B][64][L]
    const float* __restrict__ proj_W,    // [32][64]
    const float* __restrict__ proj_b,    // [32]
    const float* __restrict__ Wih_f,     // [128][32]
    const float* __restrict__ Wih_b,
    const float* __restrict__ bias2,     // [2][128]
    float* __restrict__ gx,
    int chunkT, int s0)
{
    int tilesPerB = chunkT >> 8;
    int b  = blockIdx.x / tilesPerB;
    int tt = (blockIdx.x % tilesPerB) * 256 + threadIdx.x;
    int s  = s0 + tt;

    #pragma unroll 1
    for (int d = 0; d < 2; ++d) {
        int t = d ? (LSEQ - 1 - s) : s;
        float f[INDIM];
        #pragma unroll
        for (int k = 0; k < INDIM; ++k)
            f[k] = features[((size_t)b * INDIM + k) * LSEQ + t];

        float proj[HIDN];
        #pragma unroll 1
        for (int m = 0; m < HIDN; ++m) {
            double sA = 0.0, sB = 0.0, sC = 0.0, sD = 0.0;
            #pragma unroll
            for (int k = 0; k < INDIM; k += 4) {
                sA += (double)proj_W[m * INDIM + k + 0] * (double)f[k + 0];
                sB += (double)proj_W[m * INDIM + k + 1] * (double)f[k + 1];
                sC += (double)proj_W[m * INDIM + k + 2] * (double)f[k + 2];
                sD += (double)proj_W[m * INDIM + k + 3] * (double)f[k + 3];
            }
            proj[m] = (float)(((double)proj_b[m] + sA + sB) + (sC + sD));
        }

        const float* Wih = d ? Wih_b : Wih_f;
        const float* bs  = bias2 + d * NGATE;
        float2* out2 = (float2*)(gx + (((size_t)(d * BATCH + b) * chunkT + tt) << 7));
        #pragma unroll 1
        for (int kq = 0; kq < HIDN; ++kq) {
            const float* Wi = Wih + (kq)      * HIDN;
            const float* Wf = Wih + (kq + 32) * HIDN;
            const float* Wg = Wih + (kq + 64) * HIDN;
            const float* Wo = Wih + (kq + 96) * HIDN;
            double si_e = 0, si_o = 0, sf_e = 0, sf_o = 0;
            double sg_e = 0, sg_o = 0, so_e = 0, so_o = 0;
            #pragma unroll
            for (int m = 0; m < HIDN; m += 2) {
                double pe = (double)proj[m], po = (double)proj[m + 1];
                si_e += (double)Wi[m] * pe;  si_o += (double)Wi[m + 1] * po;
                sf_e += (double)Wf[m] * pe;  sf_o += (double)Wf[m + 1] * po;
                sg_e += (double)Wg[m] * pe;  sg_o += (double)Wg[m + 1] * po;
                so_e += (double)Wo[m] * pe;  so_o += (double)Wo[m + 1] * po;
            }
            float2 vif, vgo;
            vif.x = (float)(((double)bs[kq]      + si_e) + si_o);
            vif.y = (float)(((double)bs[kq + 32] + sf_e) + sf_o);
            vgo.x = (float)(((double)bs[kq + 64] + sg_e) + sg_o);
            vgo.y = (float)(((double)bs[kq + 96] + so_e) + so_o);
            out2[kq]      = vif;
            out2[32 + kq] = vgo;
        }
    }
}

// ---------------------------------------------------------------------------
// k_rec: sequential LSTM, one single-wave workgroup per (dir, batch).
// waves_per_eu(1,1) -> 512-VGPR budget so the 64 weight values stay resident.
// Packed v_pk_fma matvec on (g0,g1); h broadcast via v_readlane; activations
// __expf + IEEE division (proven numerics class); numpy c/h rounding.
// Lane l<32 owns (i_k,f_k); lane l>=32 owns (g_k,o_k), k=l&31.
// ---------------------------------------------------------------------------
__global__ __launch_bounds__(64)
__attribute__((amdgpu_waves_per_eu(1, 1)))
void k_rec(
    const float* __restrict__ gx,      // [2][B][chunkT][64 float2] (+pad)
    const float* __restrict__ Whh_f,   // [128][32]
    const float* __restrict__ Whh_b,
    float* __restrict__ hbuf,          // [2][B][L][32] fp32
    float* __restrict__ state,         // [2][B][2][32]  (h then c)
    double* __restrict__ hsum,         // [2][B][32] fp64
    int chunkT, int s0)
{
    const int wg   = blockIdx.x;        // d*32 + b
    const int d    = wg >> 5;
    const int lane = threadIdx.x;
    const int k    = lane & 31;
    const int half = lane >> 5;         // 0: i/f rows, 1: g/o rows
    const int r0   = k + (half << 6);   // i or g row
    const int r1   = r0 + 32;           // f or o row

    // a0 activation: lo lanes sigmoid(i), hi lanes tanh(g)
    const float qA   = half ? -2.f : -1.f;
    const float numA = half ?  2.f :  1.f;
    const float addA = half ? -1.f :  0.f;

    const float* whh = d ? Whh_b : Whh_f;
    // wv[m] = (Whh[r0][m], Whh[r1][m]) — loaded via float4, paired in regs
    v2f wv[HIDN];
    #pragma unroll
    for (int q = 0; q < 8; ++q) {
        float4 a = *reinterpret_cast<const float4*>(whh + r0 * HIDN + 4 * q);
        float4 b = *reinterpret_cast<const float4*>(whh + r1 * HIDN + 4 * q);
        wv[4 * q + 0] = v2f{a.x, b.x};
        wv[4 * q + 1] = v2f{a.y, b.y};
        wv[4 * q + 2] = v2f{a.z, b.z};
        wv[4 * q + 3] = v2f{a.w, b.w};
    }

    float* st = state + (wg << 6);
    float hcur = st[k];
    float c_my = st[HIDN + k];
    double hs_my = (lane < HIDN) ? hsum[wg * HIDN + lane] : 0.0;

    const float2* gq2 = reinterpret_cast<const float2*>(gx) + ((size_t)wg * chunkT << 6);
    // 8-deep prefetch, rotated by 8-step unroll
    float2 cur[8], nxt[8];
    #pragma unroll
    for (int u = 0; u < 8; ++u) cur[u] = gq2[u * 64 + lane];

    const int t0 = d ? (LSEQ - 1 - s0) : s0;
    const int hinc = d ? -HIDN : HIDN;
    float* hp = hbuf + (((size_t)wg * LSEQ + t0) << 5) + k;

    #pragma unroll 1
    for (int tt = 0; tt < chunkT; tt += 8) {
        #pragma unroll
        for (int u = 0; u < 8; ++u) {
            // prefetch row tt+u+8 (tail reads land in the 4 KiB pad)
            nxt[u] = gq2[(u + 8) * 64 + lane];

            v2f acc = v2f{cur[u].x, cur[u].y};
            #pragma unroll
            for (int m = 0; m < HIDN; ++m) {
                float hm = readlane_f(hcur, m);         // SGPR broadcast
                acc = __builtin_elementwise_fma(wv[m], v2f{hm, hm}, acc);
            }
            float g0 = acc.x, g1 = acc.y;
            // a0 = sig(g0) lo | tanh(g0) hi   (branch-free, IEEE div)
            float e0 = __expf(qA * g0);
            float a0 = numA / (1.f + e0) + addA;
            // a1 = sig(g1): f (lo) / o (hi)
            float e1 = __expf(-g1);
            float a1 = 1.f / (1.f + e1);
            float xg = __shfl_xor(a0, 32);              // lo lanes: tanh(g_k)
            float xo = __shfl_xor(a1, 32);              // lo lanes: sig(o_k)
            // c = (f*c) + (i*g); h = o * tanh(c)   (numpy rounding pattern)
            float p1 = __fmul_rn(a1, c_my);
            float p2 = __fmul_rn(a0, xg);
            float cn = __fadd_rn(p1, p2);
            float ec = __expf(-2.f * cn);
            float tc = 2.f / (1.f + ec) - 1.f;          // tanh(c)
            float hn = __fmul_rn(xo, tc);
            c_my = cn;
            hcur = hn;
            hs_my += (double)hn;
            if (lane < HIDN) *hp = hn;
            hp += hinc;
        }
        #pragma unroll
        for (int u = 0; u < 8; ++u) cur[u] = nxt[u];
        gq2 += 8 * 64;
    }

    if (lane < HIDN) {
        st[lane] = hcur;
        st[HIDN + lane] = c_my;
        hsum[wg * HIDN + lane] = hs_my;
    }
}

// ---------------------------------------------------------------------------
// k_probs: per (b,t): h1 = relu([hf,hb] @ bc_W1.T + b1); p = sig(h1.bc_W2+b2);
//          edge *1.2; clip [0,1]. fp64 dots, 2-way chain split.
// ---------------------------------------------------------------------------
__global__ __launch_bounds__(256) void k_probs(
    const float* __restrict__ hbuf,            // [2][B][L][32] fp32
    const float* __restrict__ bcW1, const float* __restrict__ bcb1,
    const float* __restrict__ bcW2, const float* __restrict__ bcb2,
    float* __restrict__ out)
{
    int idx = blockIdx.x * 256 + threadIdx.x;   // b*L + t
    int t = idx & (LSEQ - 1);
    int b = idx >> 14;

    float h[64];
    const float* pf = hbuf + (((size_t)b * LSEQ + t) << 5);
    const float* pb = hbuf + (((size_t)(BATCH + b) * LSEQ + t) << 5);
    #pragma unroll
    for (int q = 0; q < 8; ++q) {
        float4 v = reinterpret_cast<const float4*>(pf)[q];
        h[q * 4] = v.x; h[q * 4 + 1] = v.y; h[q * 4 + 2] = v.z; h[q * 4 + 3] = v.w;
    }
    #pragma unroll
    for (int q = 0; q < 8; ++q) {
        float4 v = reinterpret_cast<const float4*>(pb)[q];
        h[32 + q * 4] = v.x; h[32 + q * 4 + 1] = v.y; h[32 + q * 4 + 2] = v.z; h[32 + q * 4 + 3] = v.w;
    }

    double a2 = (double)bcb2[0];
    #pragma unroll 1
    for (int m = 0; m < 32; ++m) {
        double ae = 0.0, ao = 0.0;
        #pragma unroll
        for (int kk = 0; kk < 64; kk += 2) {
            ae += (double)bcW1[m * 64 + kk]     * (double)h[kk];
            ao += (double)bcW1[m * 64 + kk + 1] * (double)h[kk + 1];
        }
        float af = fmaxf((float)(((double)bcb1[m] + ae) + ao), 0.f);
        a2 += (double)bcW2[m] * (double)af;
    }
    float p = fsig((float)a2);
    if (t == 0 || t == LSEQ - 1) p = __fmul_rn(p, 1.2f);
    p = fminf(fmaxf(p, 0.f), 1.f);
    out[idx] = p;
}

__global__ __launch_bounds__(256) void k_adj(
    const float* __restrict__ probs, float* __restrict__ adj)
{
    int idx = blockIdx.x * 256 + threadIdx.x;
    int t = idx & (LSEQ - 1);
    float a = 0.f;
    if (t > 0 && t < LSEQ - 1) {
        float p = probs[idx], pm = probs[idx - 1], pp = probs[idx + 1];
        float left = __fadd_rn(p, -pm), right = __fadd_rn(p, -pp);
        float al = fabsf(left), ar = fabsf(right);
        if (left < 0.f && al > ar)       a = -1.f;
        else if (right < 0.f && ar > al) a =  1.f;
    }
    adj[idx] = a;
}

__global__ __launch_bounds__(64) void k_realp(
    const double* __restrict__ hsum, const float* __restrict__ rcW,
    const float* __restrict__ rcb, float* __restrict__ out)
{
    int b = threadIdx.x;
    if (b < BATCH) {
        const double invL = 1.0 / (double)LSEQ;
        double acc = (double)rcb[0];
        #pragma unroll
        for (int kk = 0; kk < 32; ++kk) {
            acc += hsum[b * 32 + kk] * invL * (double)rcW[kk];
            acc += hsum[(BATCH + b) * 32 + kk] * invL * (double)rcW[32 + kk];
        }
        out[b] = fsig((float)acc);
    }
}

// ---------------------------------------------------------------------------
extern "C" void kernel_launch(void* const* d_in, const int* in_sizes, int n_in,
                              void* d_out, int out_size, void* d_ws, size_t ws_size,
                              hipStream_t stream)
{
    (void)in_sizes; (void)n_in; (void)out_size;
    const float* features = (const float*)d_in[0];
    const float* proj_W   = (const float*)d_in[1];
    const float* proj_b   = (const float*)d_in[2];
    const float* Wih_f    = (const float*)d_in[3];
    const float* Whh_f    = (const float*)d_in[4];
    const float* bih_f    = (const float*)d_in[5];
    const float* bhh_f    = (const float*)d_in[6];
    const float* Wih_b    = (const float*)d_in[7];
    const float* Whh_b    = (const float*)d_in[8];
    const float* bih_b    = (const float*)d_in[9];
    const float* bhh_b    = (const float*)d_in[10];
    const float* bcW1     = (const float*)d_in[11];
    const float* bcb1     = (const float*)d_in[12];
    const float* bcW2     = (const float*)d_in[13];
    const float* bcb2     = (const float*)d_in[14];
    const float* rcW      = (const float*)d_in[15];
    const float* rcb      = (const float*)d_in[16];

    char* ws = (char*)d_ws;
    float*  bias2 = (float*)(ws + 65536);              // 1 KiB
    double* hsum  = (double*)(ws + 66560);             // 16 KiB (fp64)
    float*  state = (float*)(ws + 82944);              // 16 KiB
    const size_t HBYTES = (size_t)2 * BATCH * LSEQ * HIDN * sizeof(float); // 128 MiB
    float* hbuf  = (float*)(ws + (1u << 20));
    float* gxbuf = (float*)(ws + (1u << 20) + HBYTES);
    const size_t GXOFF = (1u << 20) + HBYTES;

    // deterministic chunk choice from ws_size; cap at 4096 so the gx chunk
    // stays L3-resident between k_gx and k_rec
    int chunkT = 4096;
    for (;;) {
        size_t need = GXOFF + (size_t)2 * BATCH * (size_t)chunkT * NGATE * 4 + 4096;
        if (need <= ws_size || chunkT <= 256) break;
        chunkT >>= 1;
    }
    const int nch = LSEQ / chunkT;

    float* outp = (float*)d_out;
    const int BL = BATCH * LSEQ;

    k_prep<<<16, 256, 0, stream>>>(bih_f, bhh_f, bih_b, bhh_b, bias2, hsum, state);
    for (int c = 0; c < nch; ++c) {
        int s0 = c * chunkT;
        k_gx<<<BATCH * (chunkT >> 8), 256, 0, stream>>>(features, proj_W, proj_b,
                                                        Wih_f, Wih_b, bias2, gxbuf, chunkT, s0);
        k_rec<<<64, 64, 0, stream>>>(gxbuf, Whh_f, Whh_b, hbuf, state, hsum, chunkT, s0);
    }
    k_probs<<<BL / 256, 256, 0, stream>>>(hbuf, bcW1, bcb1, bcW2, bcb2, outp);
    k_adj<<<BL / 256, 256, 0, stream>>>(outp, outp + BL);
    k_realp<<<1, 64, 0, stream>>>(hsum, rcW, rcb, outp + 2 * BL);
}

// Round 10
// 5210.191 us; speedup vs baseline: 2.3283x; 1.4395x over previous
//
#include <hip/hip_runtime.h>
#include <hip/hip_bf16.h>
#include <stdint.h>

#define LSEQ   16384
#define BATCH  32
#define HIDN   32
#define NGATE  128   // 4*HIDN
#define INDIM  64

typedef float v2f __attribute__((ext_vector_type(2)));

// libm-accurate sigmoid for the small output kernels.
__device__ __forceinline__ float fsig(float x) { return 1.f / (1.f + expf(-x)); }

__device__ __forceinline__ float readlane_f(float v, int l) {
    return __uint_as_float((unsigned)__builtin_amdgcn_readlane((int)__float_as_uint(v), l));
}

// ---------------------------------------------------------------------------
// k_prep: bias2[d][j] = bih[j] + bhh[j]; zero hsum (fp64) and h/c state.
// ---------------------------------------------------------------------------
__global__ __launch_bounds__(256) void k_prep(
    const float* __restrict__ bih_f, const float* __restrict__ bhh_f,
    const float* __restrict__ bih_b, const float* __restrict__ bhh_b,
    float* __restrict__ bias2, double* __restrict__ hsum, float* __restrict__ state)
{
    int gid = blockIdx.x * 256 + threadIdx.x;   // [0, 4096)
    if (gid < 256) {
        int dd = gid >> 7, jj = gid & 127;
        float bi = dd ? bih_b[jj] : bih_f[jj];
        float bh = dd ? bhh_b[jj] : bhh_f[jj];
        bias2[gid] = __fadd_rn(bi, bh);
    }
    if (gid < 2 * BATCH * HIDN) hsum[gid] = 0.0;
    state[gid] = 0.f;   // 4096 = 2*B*2*32
}

// ---------------------------------------------------------------------------
// gx device body: exact (fp64) dots rounded to fp32 where numpy rounds.
// BIT-IDENTICAL to the R8-passing k_gx. Store layout:
//   out2[k]    = (i_k, f_k)     k in [0,32)
//   out2[32+k] = (g_k, o_k)
// ---------------------------------------------------------------------------
__device__ __forceinline__ void gx_device(
    const float* __restrict__ features,  // [B][64][L]
    const float* __restrict__ proj_W,    // [32][64]
    const float* __restrict__ proj_b,    // [32]
    const float* __restrict__ Wih_f,     // [128][32]
    const float* __restrict__ Wih_b,
    const float* __restrict__ bias2,     // [2][128]
    float* __restrict__ gx,
    int chunkT, int s0, int blk, int tid)
{
    int tilesPerB = chunkT >> 8;
    int b  = blk / tilesPerB;
    int tt = (blk % tilesPerB) * 256 + tid;
    int s  = s0 + tt;

    #pragma unroll 1
    for (int d = 0; d < 2; ++d) {
        int t = d ? (LSEQ - 1 - s) : s;
        float f[INDIM];
        #pragma unroll
        for (int k = 0; k < INDIM; ++k)
            f[k] = features[((size_t)b * INDIM + k) * LSEQ + t];

        float proj[HIDN];
        #pragma unroll 1
        for (int m = 0; m < HIDN; ++m) {
            double sA = 0.0, sB = 0.0, sC = 0.0, sD = 0.0;
            #pragma unroll
            for (int k = 0; k < INDIM; k += 4) {
                sA += (double)proj_W[m * INDIM + k + 0] * (double)f[k + 0];
                sB += (double)proj_W[m * INDIM + k + 1] * (double)f[k + 1];
                sC += (double)proj_W[m * INDIM + k + 2] * (double)f[k + 2];
                sD += (double)proj_W[m * INDIM + k + 3] * (double)f[k + 3];
            }
            proj[m] = (float)(((double)proj_b[m] + sA + sB) + (sC + sD));
        }

        const float* Wih = d ? Wih_b : Wih_f;
        const float* bs  = bias2 + d * NGATE;
        float2* out2 = (float2*)(gx + (((size_t)(d * BATCH + b) * chunkT + tt) << 7));
        #pragma unroll 1
        for (int kq = 0; kq < HIDN; ++kq) {
            const float* Wi = Wih + (kq)      * HIDN;
            const float* Wf = Wih + (kq + 32) * HIDN;
            const float* Wg = Wih + (kq + 64) * HIDN;
            const float* Wo = Wih + (kq + 96) * HIDN;
            double si_e = 0, si_o = 0, sf_e = 0, sf_o = 0;
            double sg_e = 0, sg_o = 0, so_e = 0, so_o = 0;
            #pragma unroll
            for (int m = 0; m < HIDN; m += 2) {
                double pe = (double)proj[m], po = (double)proj[m + 1];
                si_e += (double)Wi[m] * pe;  si_o += (double)Wi[m + 1] * po;
                sf_e += (double)Wf[m] * pe;  sf_o += (double)Wf[m + 1] * po;
                sg_e += (double)Wg[m] * pe;  sg_o += (double)Wg[m + 1] * po;
                so_e += (double)Wo[m] * pe;  so_o += (double)Wo[m + 1] * po;
            }
            float2 vif, vgo;
            vif.x = (float)(((double)bs[kq]      + si_e) + si_o);
            vif.y = (float)(((double)bs[kq + 32] + sf_e) + sf_o);
            vgo.x = (float)(((double)bs[kq + 64] + sg_e) + sg_o);
            vgo.y = (float)(((double)bs[kq + 96] + so_e) + so_o);
            out2[kq]      = vif;
            out2[32 + kq] = vgo;
        }
    }
}

__global__ __launch_bounds__(256) void k_gx(
    const float* __restrict__ features, const float* __restrict__ proj_W,
    const float* __restrict__ proj_b, const float* __restrict__ Wih_f,
    const float* __restrict__ Wih_b, const float* __restrict__ bias2,
    float* __restrict__ gx, int chunkT, int s0)
{
    gx_device(features, proj_W, proj_b, Wih_f, Wih_b, bias2, gx,
              chunkT, s0, blockIdx.x, threadIdx.x);
}

// ---------------------------------------------------------------------------
// One LSTM step — numerics BITWISE identical to the R8-passing version:
// sequential m=0..31 pk-fma chain, __expf + IEEE div activations, numpy
// c/h rounding. Only change: readlanes hoisted ahead of the chain
// (pure scheduling; identical values).
// ---------------------------------------------------------------------------
#define LSTM_STEP(CURV, IDX) do {                                             \
    float hm[HIDN];                                                           \
    _Pragma("unroll")                                                         \
    for (int m = 0; m < HIDN; ++m) hm[m] = readlane_f(hcur, m);               \
    v2f acc = v2f{(CURV).x, (CURV).y};                                        \
    _Pragma("unroll")                                                         \
    for (int m = 0; m < HIDN; ++m)                                            \
        acc = __builtin_elementwise_fma(wv[m], v2f{hm[m], hm[m]}, acc);       \
    float g0 = acc.x, g1 = acc.y;                                             \
    float e0 = __expf(qA * g0);                                               \
    float a0 = numA / (1.f + e0) + addA;                                      \
    float e1 = __expf(-g1);                                                   \
    float a1 = 1.f / (1.f + e1);                                              \
    float xg = __shfl_xor(a0, 32);                                            \
    float xo = __shfl_xor(a1, 32);                                            \
    float p1 = __fmul_rn(a1, c_my);                                           \
    float p2 = __fmul_rn(a0, xg);                                             \
    float cn = __fadd_rn(p1, p2);                                             \
    float ec = __expf(-2.f * cn);                                             \
    float tc = 2.f / (1.f + ec) - 1.f;                                        \
    float hn = __fmul_rn(xo, tc);                                             \
    c_my = cn; hcur = hn;                                                     \
    hs_my += (double)hn;                                                      \
    if (lane < HIDN) hp[(IDX) * HSTEP * HIDN] = hn;                           \
} while (0)

// Main recurrence loop; direction templated so h-store offsets are immediates.
// Ping-pong A/B prefetch (distance 8, no rotation copies).
template<int HSTEP>
__device__ __forceinline__ void rec_body(
    const float2* __restrict__ gq2, float* __restrict__ hp,
    v2f (&wv)[HIDN], float qA, float numA, float addA,
    float& hcur, float& c_my, double& hs_my,
    int chunkT, int lane)
{
    float2 A[8], B[8];
    #pragma unroll
    for (int u = 0; u < 8; ++u) A[u] = gq2[u * 64 + lane];

    #pragma unroll 1
    for (int tt = 0; tt < chunkT; tt += 16) {
        #pragma unroll
        for (int u = 0; u < 8; ++u) {
            B[u] = gq2[(u + 8) * 64 + lane];        // rows tt+8..tt+15
            LSTM_STEP(A[u], u);
        }
        #pragma unroll
        for (int u = 0; u < 8; ++u) {
            A[u] = gq2[(u + 16) * 64 + lane];       // rows tt+16..tt+23 (pad at tail)
            LSTM_STEP(B[u], 8 + u);
        }
        gq2 += 16 * 64;
        hp  += 16 * HSTEP * HIDN;
    }
}

// ---------------------------------------------------------------------------
// k_fused: blocks 0..63 = recurrence (1 wave, threads 0-63, setprio 1) reading
// gxSrc; blocks 64+ = gx for the NEXT chunk into gxDst (disjoint buffer, no
// sync needed). gx values bit-identical to standalone k_gx (same device fn).
// ---------------------------------------------------------------------------
__global__ __launch_bounds__(256)
__attribute__((amdgpu_waves_per_eu(1)))
void k_fused(
    const float* __restrict__ gxSrc,   // [2][B][chunkT][64 float2] (+pad)
    float* __restrict__ gxDst,
    const float* __restrict__ features, const float* __restrict__ proj_W,
    const float* __restrict__ proj_b, const float* __restrict__ Wih_f,
    const float* __restrict__ Wih_b, const float* __restrict__ bias2,
    const float* __restrict__ Whh_f,   // [128][32]
    const float* __restrict__ Whh_b,
    float* __restrict__ hbuf,          // [2][B][L][32] fp32
    float* __restrict__ state,         // [2][B][2][32]  (h then c)
    double* __restrict__ hsum,         // [2][B][32] fp64
    int chunkT, int s0_rec, int s0_gx)
{
    if (blockIdx.x >= 64) {
        gx_device(features, proj_W, proj_b, Wih_f, Wih_b, bias2, gxDst,
                  chunkT, s0_gx, blockIdx.x - 64, threadIdx.x);
        return;
    }
    if (threadIdx.x >= 64) return;
    __builtin_amdgcn_s_setprio(1);      // favor rec wave over co-resident gx waves

    const int wg   = blockIdx.x;        // d*32 + b
    const int d    = wg >> 5;
    const int lane = threadIdx.x;
    const int k    = lane & 31;
    const int half = lane >> 5;         // 0: i/f rows, 1: g/o rows
    const int r0   = k + (half << 6);   // i or g row
    const int r1   = r0 + 32;           // f or o row

    // a0 activation: lo lanes sigmoid(i), hi lanes tanh(g)
    const float qA   = half ? -2.f : -1.f;
    const float numA = half ?  2.f :  1.f;
    const float addA = half ? -1.f :  0.f;

    const float* whh = d ? Whh_b : Whh_f;
    // wv[m] = (Whh[r0][m], Whh[r1][m]) — loaded via float4, paired in regs
    v2f wv[HIDN];
    #pragma unroll
    for (int q = 0; q < 8; ++q) {
        float4 a = *reinterpret_cast<const float4*>(whh + r0 * HIDN + 4 * q);
        float4 b = *reinterpret_cast<const float4*>(whh + r1 * HIDN + 4 * q);
        wv[4 * q + 0] = v2f{a.x, b.x};
        wv[4 * q + 1] = v2f{a.y, b.y};
        wv[4 * q + 2] = v2f{a.z, b.z};
        wv[4 * q + 3] = v2f{a.w, b.w};
    }

    float* st = state + (wg << 6);
    float hcur = st[k];
    float c_my = st[HIDN + k];
    double hs_my = (lane < HIDN) ? hsum[wg * HIDN + lane] : 0.0;

    const float2* gq2 = reinterpret_cast<const float2*>(gxSrc) + ((size_t)wg * chunkT << 6);
    const int t0 = d ? (LSEQ - 1 - s0_rec) : s0_rec;
    float* hp = hbuf + (((size_t)wg * LSEQ + t0) << 5) + k;

    if (d == 0)
        rec_body<+1>(gq2, hp, wv, qA, numA, addA, hcur, c_my, hs_my, chunkT, lane);
    else
        rec_body<-1>(gq2, hp, wv, qA, numA, addA, hcur, c_my, hs_my, chunkT, lane);

    if (lane < HIDN) {
        st[lane] = hcur;
        st[HIDN + lane] = c_my;
        hsum[wg * HIDN + lane] = hs_my;
    }
}

// ---------------------------------------------------------------------------
// k_probs: per (b,t): h1 = relu([hf,hb] @ bc_W1.T + b1); p = sig(h1.bc_W2+b2);
//          edge *1.2; clip [0,1]. fp64 dots, 2-way chain split.
// ---------------------------------------------------------------------------
__global__ __launch_bounds__(256) void k_probs(
    const float* __restrict__ hbuf,            // [2][B][L][32] fp32
    const float* __restrict__ bcW1, const float* __restrict__ bcb1,
    const float* __restrict__ bcW2, const float* __restrict__ bcb2,
    float* __restrict__ out)
{
    int idx = blockIdx.x * 256 + threadIdx.x;   // b*L + t
    int t = idx & (LSEQ - 1);
    int b = idx >> 14;

    float h[64];
    const float* pf = hbuf + (((size_t)b * LSEQ + t) << 5);
    const float* pb = hbuf + (((size_t)(BATCH + b) * LSEQ + t) << 5);
    #pragma unroll
    for (int q = 0; q < 8; ++q) {
        float4 v = reinterpret_cast<const float4*>(pf)[q];
        h[q * 4] = v.x; h[q * 4 + 1] = v.y; h[q * 4 + 2] = v.z; h[q * 4 + 3] = v.w;
    }
    #pragma unroll
    for (int q = 0; q < 8; ++q) {
        float4 v = reinterpret_cast<const float4*>(pb)[q];
        h[32 + q * 4] = v.x; h[32 + q * 4 + 1] = v.y; h[32 + q * 4 + 2] = v.z; h[32 + q * 4 + 3] = v.w;
    }

    double a2 = (double)bcb2[0];
    #pragma unroll 1
    for (int m = 0; m < 32; ++m) {
        double ae = 0.0, ao = 0.0;
        #pragma unroll
        for (int kk = 0; kk < 64; kk += 2) {
            ae += (double)bcW1[m * 64 + kk]     * (double)h[kk];
            ao += (double)bcW1[m * 64 + kk + 1] * (double)h[kk + 1];
        }
        float af = fmaxf((float)(((double)bcb1[m] + ae) + ao), 0.f);
        a2 += (double)bcW2[m] * (double)af;
    }
    float p = fsig((float)a2);
    if (t == 0 || t == LSEQ - 1) p = __fmul_rn(p, 1.2f);
    p = fminf(fmaxf(p, 0.f), 1.f);
    out[idx] = p;
}

__global__ __launch_bounds__(256) void k_adj(
    const float* __restrict__ probs, float* __restrict__ adj)
{
    int idx = blockIdx.x * 256 + threadIdx.x;
    int t = idx & (LSEQ - 1);
    float a = 0.f;
    if (t > 0 && t < LSEQ - 1) {
        float p = probs[idx], pm = probs[idx - 1], pp = probs[idx + 1];
        float left = __fadd_rn(p, -pm), right = __fadd_rn(p, -pp);
        float al = fabsf(left), ar = fabsf(right);
        if (left < 0.f && al > ar)       a = -1.f;
        else if (right < 0.f && ar > al) a =  1.f;
    }
    adj[idx] = a;
}

__global__ __launch_bounds__(64) void k_realp(
    const double* __restrict__ hsum, const float* __restrict__ rcW,
    const float* __restrict__ rcb, float* __restrict__ out)
{
    int b = threadIdx.x;
    if (b < BATCH) {
        const double invL = 1.0 / (double)LSEQ;
        double acc = (double)rcb[0];
        #pragma unroll
        for (int kk = 0; kk < 32; ++kk) {
            acc += hsum[b * 32 + kk] * invL * (double)rcW[kk];
            acc += hsum[(BATCH + b) * 32 + kk] * invL * (double)rcW[32 + kk];
        }
        out[b] = fsig((float)acc);
    }
}

// ---------------------------------------------------------------------------
extern "C" void kernel_launch(void* const* d_in, const int* in_sizes, int n_in,
                              void* d_out, int out_size, void* d_ws, size_t ws_size,
                              hipStream_t stream)
{
    (void)in_sizes; (void)n_in; (void)out_size;
    const float* features = (const float*)d_in[0];
    const float* proj_W   = (const float*)d_in[1];
    const float* proj_b   = (const float*)d_in[2];
    const float* Wih_f    = (const float*)d_in[3];
    const float* Whh_f    = (const float*)d_in[4];
    const float* bih_f    = (const float*)d_in[5];
    const float* bhh_f    = (const float*)d_in[6];
    const float* Wih_b    = (const float*)d_in[7];
    const float* Whh_b    = (const float*)d_in[8];
    const float* bih_b    = (const float*)d_in[9];
    const float* bhh_b    = (const float*)d_in[10];
    const float* bcW1     = (const float*)d_in[11];
    const float* bcb1     = (const float*)d_in[12];
    const float* bcW2     = (const float*)d_in[13];
    const float* bcb2     = (const float*)d_in[14];
    const float* rcW      = (const float*)d_in[15];
    const float* rcb      = (const float*)d_in[16];

    char* ws = (char*)d_ws;
    float*  bias2 = (float*)(ws + 65536);              // 1 KiB
    double* hsum  = (double*)(ws + 66560);             // 16 KiB (fp64)
    float*  state = (float*)(ws + 82944);              // 16 KiB
    const size_t HBYTES = (size_t)2 * BATCH * LSEQ * HIDN * sizeof(float); // 128 MiB
    float* hbuf = (float*)(ws + (1u << 20));
    const size_t GXOFF = (1u << 20) + HBYTES;

    // chunkT selection: largest pow2 whose DOUBLE-buffered gx fits (pipelined
    // mode); else single-buffer serial fallback. Deterministic from ws_size.
    auto gxstride = [](int c) { return (size_t)c * 32768 + 16384; };
    int chunkT = LSEQ;
    bool dbuf = true;
    while (chunkT > 256 && GXOFF + 2 * gxstride(chunkT) > ws_size) chunkT >>= 1;
    if (GXOFF + 2 * gxstride(chunkT) > ws_size) {
        dbuf = false;
        chunkT = LSEQ;
        while (chunkT > 256 && GXOFF + gxstride(chunkT) > ws_size) chunkT >>= 1;
    }
    const int nch = LSEQ / chunkT;
    float* gx0 = (float*)(ws + GXOFF);
    float* gx1 = dbuf ? (float*)(ws + GXOFF + gxstride(chunkT)) : gx0;

    float* outp = (float*)d_out;
    const int BL = BATCH * LSEQ;
    const int gxblocks = BATCH * (chunkT >> 8);

    k_prep<<<16, 256, 0, stream>>>(bih_f, bhh_f, bih_b, bhh_b, bias2, hsum, state);
    k_gx<<<gxblocks, 256, 0, stream>>>(features, proj_W, proj_b,
                                       Wih_f, Wih_b, bias2, gx0, chunkT, 0);
    for (int c = 0; c < nch; ++c) {
        float* src = (c & 1) ? gx1 : gx0;
        float* dst = (c & 1) ? gx0 : gx1;
        if (dbuf) {
            bool more = (c + 1 < nch);
            k_fused<<<64 + (more ? gxblocks : 0), 256, 0, stream>>>(
                src, dst, features, proj_W, proj_b, Wih_f, Wih_b, bias2,
                Whh_f, Whh_b, hbuf, state, hsum,
                chunkT, c * chunkT, (c + 1) * chunkT);
        } else {
            if (c > 0)
                k_gx<<<gxblocks, 256, 0, stream>>>(features, proj_W, proj_b,
                                                   Wih_f, Wih_b, bias2, gx0,
                                                   chunkT, c * chunkT);
            k_fused<<<64, 256, 0, stream>>>(
                gx0, gx0, features, proj_W, proj_b, Wih_f, Wih_b, bias2,
                Whh_f, Whh_b, hbuf, state, hsum,
                chunkT, c * chunkT, 0);
        }
    }
    k_probs<<<BL / 256, 256, 0, stream>>>(hbuf, bcW1, bcb1, bcW2, bcb2, outp);
    k_adj<<<BL / 256, 256, 0, stream>>>(outp, outp + BL);
    k_realp<<<1, 64, 0, stream>>>(hsum, rcW, rcb, outp + 2 * BL);
}